// Round 3
// baseline (1589.029 us; speedup 1.0000x reference)
//
#include <hip/hip_runtime.h>

// GCNConv(8->64), self-loops, symmetric norm.
// out[c] = ( sum_e dis[r]*ew*dis[c]*x[r] + dis[c]^2*x[c] ) @ W + b
//
// Strategy: XCD-local aggregation. Destinations are partitioned by
// p(c) = (c>>9)&7 (512-node chunks, 64B-line-aligned for both deg and agg).
// Each block discovers its physical XCD (HW_REG_XCC_ID) and handles only
// edges whose dest is in its XCD's partition, using WORKGROUP-scope f32
// atomics -> RMW executes in the local (coherent-for-us) L2 instead of at
// the fabric. Work is deduplicated via per-XCD chunk cursors; any range not
// drained (XCD got no blocks) is finished by a fallback kernel with
// device-scope atomics, so correctness never depends on XCD assignment.

#define PSHIFT 9
#define CHUNK 4096

__device__ __forceinline__ int get_xcd() {
    unsigned v;
    asm volatile("s_getreg_b32 %0, hwreg(HW_REG_XCC_ID)" : "=s"(v));
    return (int)(v & 7u);
}

__device__ __forceinline__ void wg_fadd(float* p, float v) {
    __hip_atomic_fetch_add(p, v, __ATOMIC_RELAXED, __HIP_MEMORY_SCOPE_WORKGROUP);
}

// setup: deg=1 (self-loop), agg=0, cursors=0, int64-vs-int32 detect (block 0)
__global__ void setup_k(const unsigned* w, unsigned* orw, unsigned* cur,
                        float* deg, float4* agg4, int N) {
    int t = blockIdx.x * blockDim.x + threadIdx.x;
    int st = gridDim.x * blockDim.x;
    for (int i = t; i < N; i += st) deg[i] = 1.0f;
    for (int i = t; i < 2 * N; i += st) agg4[i] = make_float4(0.f, 0.f, 0.f, 0.f);
    if (blockIdx.x == 0) {
        if (threadIdx.x < 16) cur[threadIdx.x] = 0u;
        __shared__ unsigned s;
        if (threadIdx.x == 0) s = 0u;
        __syncthreads();
        unsigned v = 0;
        #pragma unroll
        for (int j = 0; j < 8; ++j)
            v |= w[2 * (threadIdx.x * 8 + j) + 1];
        atomicOr(&s, v);
        __syncthreads();
        if (threadIdx.x == 0) *orw = s;   // 0 => int64 layout
    }
}

// pass A: deg[c] += ew, XCD-local
__global__ void covA_k(const void* ei, const float* ea, const unsigned* orw,
                       unsigned* cur, float* deg, int E) {
    const bool is64 = (*orw == 0u);
    const int* e32 = (const int*)ei;
    const long long* e64 = (const long long*)ei;
    const int xcd = get_xcd();
    __shared__ unsigned sbase;
    for (;;) {
        if (threadIdx.x == 0) sbase = atomicAdd(&cur[xcd], (unsigned)CHUNK);
        __syncthreads();
        unsigned base = sbase;
        __syncthreads();
        if (base >= (unsigned)E) break;
        int end = min((int)base + CHUNK, E);
        for (int e = (int)base + threadIdx.x; e < end; e += blockDim.x) {
            int c = is64 ? (int)e64[E + e] : e32[E + e];
            if (((c >> PSHIFT) & 7) == xcd) wg_fadd(&deg[c], ea[e]);
        }
    }
}

// fallback A: drain any un-drained cursor ranges with device-scope atomics
__global__ void fixA_k(const void* ei, const float* ea, const unsigned* orw,
                       unsigned* cur, float* deg, int E) {
    bool need = false;
    #pragma unroll
    for (int p = 0; p < 8; ++p)
        if (cur[p] < (unsigned)E) need = true;
    if (!need) return;
    const bool is64 = (*orw == 0u);
    const int* e32 = (const int*)ei;
    const long long* e64 = (const long long*)ei;
    __shared__ unsigned sbase;
    for (int p = 0; p < 8; ++p) {
        for (;;) {
            if (threadIdx.x == 0) sbase = atomicAdd(&cur[p], (unsigned)CHUNK);
            __syncthreads();
            unsigned base = sbase;
            __syncthreads();
            if (base >= (unsigned)E) break;
            int end = min((int)base + CHUNK, E);
            for (int e = (int)base + threadIdx.x; e < end; e += blockDim.x) {
                int c = is64 ? (int)e64[E + e] : e32[E + e];
                if (((c >> PSHIFT) & 7) == p) atomicAdd(&deg[c], ea[e]);
            }
        }
    }
}

__global__ void dis_k(float* deg, int N) {
    int i = blockIdx.x * blockDim.x + threadIdx.x;
    int st = gridDim.x * blockDim.x;
    for (; i < N; i += st) {
        float d = deg[i];
        deg[i] = (d > 0.f) ? rsqrtf(d) : 0.f;
    }
}

// pass B: agg[c][0..7] += dis[r]*ew*dis[c]*x[r][0..7], XCD-local
__global__ void covB_k(const void* ei, const float* ea, const unsigned* orw,
                       unsigned* cur, const float* dis, const float* x,
                       float* agg, int E) {
    const bool is64 = (*orw == 0u);
    const int* e32 = (const int*)ei;
    const long long* e64 = (const long long*)ei;
    const int xcd = get_xcd();
    __shared__ unsigned sbase;
    for (;;) {
        if (threadIdx.x == 0) sbase = atomicAdd(&cur[8 + xcd], (unsigned)CHUNK);
        __syncthreads();
        unsigned base = sbase;
        __syncthreads();
        if (base >= (unsigned)E) break;
        int end = min((int)base + CHUNK, E);
        for (int e = (int)base + threadIdx.x; e < end; e += blockDim.x) {
            int c = is64 ? (int)e64[E + e] : e32[E + e];
            if (((c >> PSHIFT) & 7) != xcd) continue;
            int r = is64 ? (int)e64[e] : e32[e];
            float nrm = dis[r] * ea[e] * dis[c];
            const float4* xr = (const float4*)(x + (size_t)r * 8);
            float4 a = xr[0];
            float4 b = xr[1];
            float* ag = agg + (size_t)c * 8;
            wg_fadd(ag + 0, nrm * a.x); wg_fadd(ag + 1, nrm * a.y);
            wg_fadd(ag + 2, nrm * a.z); wg_fadd(ag + 3, nrm * a.w);
            wg_fadd(ag + 4, nrm * b.x); wg_fadd(ag + 5, nrm * b.y);
            wg_fadd(ag + 6, nrm * b.z); wg_fadd(ag + 7, nrm * b.w);
        }
    }
}

__global__ void fixB_k(const void* ei, const float* ea, const unsigned* orw,
                       unsigned* cur, const float* dis, const float* x,
                       float* agg, int E) {
    bool need = false;
    #pragma unroll
    for (int p = 0; p < 8; ++p)
        if (cur[8 + p] < (unsigned)E) need = true;
    if (!need) return;
    const bool is64 = (*orw == 0u);
    const int* e32 = (const int*)ei;
    const long long* e64 = (const long long*)ei;
    __shared__ unsigned sbase;
    for (int p = 0; p < 8; ++p) {
        for (;;) {
            if (threadIdx.x == 0) sbase = atomicAdd(&cur[8 + p], (unsigned)CHUNK);
            __syncthreads();
            unsigned base = sbase;
            __syncthreads();
            if (base >= (unsigned)E) break;
            int end = min((int)base + CHUNK, E);
            for (int e = (int)base + threadIdx.x; e < end; e += blockDim.x) {
                int c = is64 ? (int)e64[E + e] : e32[E + e];
                if (((c >> PSHIFT) & 7) != p) continue;
                int r = is64 ? (int)e64[e] : e32[e];
                float nrm = dis[r] * ea[e] * dis[c];
                const float4* xr = (const float4*)(x + (size_t)r * 8);
                float4 a = xr[0];
                float4 b = xr[1];
                float* ag = agg + (size_t)c * 8;
                atomicAdd(ag + 0, nrm * a.x); atomicAdd(ag + 1, nrm * a.y);
                atomicAdd(ag + 2, nrm * a.z); atomicAdd(ag + 3, nrm * a.w);
                atomicAdd(ag + 4, nrm * b.x); atomicAdd(ag + 5, nrm * b.y);
                atomicAdd(ag + 6, nrm * b.z); atomicAdd(ag + 7, nrm * b.w);
            }
        }
    }
}

// 8->64 dense transform + self-loop term, one wave per node row
__global__ void out_k(const float* x, const float* Wm, const float* bv,
                      const float* dis, const float* agg, float* out, int N) {
    int lane = threadIdx.x & 63;
    int wid = blockIdx.x * (blockDim.x >> 6) + (threadIdx.x >> 6);
    int nw = gridDim.x * (blockDim.x >> 6);
    float wreg[8];
    #pragma unroll
    for (int k = 0; k < 8; ++k) wreg[k] = Wm[k * 64 + lane];
    float bj = bv[lane];
    for (int i = wid; i < N; i += nw) {
        float d = dis[i];
        float ink = 0.f;
        if (lane < 8) ink = agg[(size_t)i * 8 + lane] + d * d * x[(size_t)i * 8 + lane];
        float acc = bj;
        #pragma unroll
        for (int k = 0; k < 8; ++k)
            acc += __shfl(ink, k) * wreg[k];
        out[(size_t)i * 64 + lane] = acc;
    }
}

extern "C" void kernel_launch(void* const* d_in, const int* in_sizes, int n_in,
                              void* d_out, int out_size, void* d_ws, size_t ws_size,
                              hipStream_t stream) {
    const float* x  = (const float*)d_in[0];
    const void*  ei = d_in[1];
    const float* ea = (const float*)d_in[2];
    const float* Wm = (const float*)d_in[3];
    const float* bv = (const float*)d_in[4];
    float* out = (float*)d_out;

    const int N = in_sizes[0] / 8;
    const int E = in_sizes[2];

    char* ws = (char*)d_ws;
    unsigned* orw = (unsigned*)ws;            // ws[0..63]   : detect word
    unsigned* cur = (unsigned*)(ws + 64);     // ws[64..127] : 16 cursors
    float* dis = (float*)(ws + 256);          // deg, then dis in place
    size_t agg_off = (256 + (size_t)N * 4 + 255) & ~(size_t)255;
    float* agg = (float*)(ws + agg_off);

    setup_k<<<512, 256, 0, stream>>>((const unsigned*)ei, orw, cur, dis,
                                     (float4*)agg, N);
    covA_k<<<2048, 256, 0, stream>>>(ei, ea, orw, cur, dis, E);
    fixA_k<<<256, 256, 0, stream>>>(ei, ea, orw, cur, dis, E);
    dis_k<<<(N + 255) / 256, 256, 0, stream>>>(dis, N);
    covB_k<<<2048, 256, 0, stream>>>(ei, ea, orw, cur, dis, x, agg, E);
    fixB_k<<<256, 256, 0, stream>>>(ei, ea, orw, cur, dis, x, agg, E);
    out_k<<<2048, 256, 0, stream>>>(x, Wm, bv, dis, agg, out, N);
}

// Round 4
// 276.755 us; speedup vs baseline: 5.7416x; 5.7416x over previous
//
#include <hip/hip_runtime.h>

// GCNConv(8->64), self-loops, symmetric norm.
// out[c] = ( dis[c] * sum_e dis[r]*ew*x[r]  +  dis[c]^2 * x[c] ) @ W + b
//
// Structure: counting sort of edges by 256-node destination bin, done
// tile-locally in LDS so global payload writes are coalesced full-line runs
// (round-2's scat_k wrote 198MB for 25.6MB of payload: 64B line per random
// 8B store). Then per-bin kernels aggregate in LDS with ZERO global float
// atomics, and fuse rsqrt / 8->64 transform / self-loop / bias.
//
// Payload pack (u64): ew_bits(32) | row(24) | lcol(8). Valid for N <= 2^24.

#define NBMAX 1024          // max bins => N <= 262144
#define BINSZ 256
#define TILE  12288         // edges per scatter tile (LDS: 96KB payload)
#define EPT   12            // TILE / 1024 threads

static inline size_t ws_align(size_t x) { return (x + 255) & ~(size_t)255; }

// ---- init: zero bin counters + detect int64-vs-int32 edge_index ----
__global__ void init_k(const unsigned* w, unsigned* orw, unsigned* cnt, int NB, int E) {
    int t = threadIdx.x;              // 256 threads, 1 block
    for (int i = t; i < NBMAX; i += 256) cnt[i] = 0u;
    __shared__ unsigned s;
    if (t == 0) s = 0u;
    __syncthreads();
    unsigned v = 0;
    int lim = (E < 2048) ? E : 2048;  // stay inside buffer even if int32
    for (int i = t; i < lim; i += 256)
        v |= w[2 * i + 1];            // odd words == 0 iff int64 layout
    atomicOr(&s, v);
    __syncthreads();
    if (t == 0) *orw = s;             // 0 => int64
}

// ---- histogram over destination bins ----
__global__ void hist_k(const void* ei, const unsigned* orw, unsigned* cnt,
                       int E, int NB) {
    __shared__ unsigned lh[NBMAX];
    const bool is64 = (*orw == 0u);
    const int* e32 = (const int*)ei;
    const long long* e64 = (const long long*)ei;
    for (int i = threadIdx.x; i < NB; i += blockDim.x) lh[i] = 0u;
    __syncthreads();
    int t = blockIdx.x * blockDim.x + threadIdx.x;
    int st = gridDim.x * blockDim.x;
    for (int e = t; e < E; e += st) {
        int c = is64 ? (int)e64[E + e] : e32[E + e];
        atomicAdd(&lh[c >> 8], 1u);
    }
    __syncthreads();
    for (int i = threadIdx.x; i < NB; i += blockDim.x) {
        unsigned v = lh[i];
        if (v) atomicAdd(&cnt[i], v);
    }
}

// ---- exclusive scan of cnt[NB] -> offs[NB+1], seed cursors ----
__global__ void scan_k(const unsigned* cnt, unsigned* offs, unsigned* gcur, int NB) {
    __shared__ unsigned sc[NBMAX];
    int t = threadIdx.x;              // 1024 threads, 1 block
    unsigned v0 = (t < NB) ? cnt[t] : 0u;
    sc[t] = v0;
    __syncthreads();
    for (int d = 1; d < 1024; d <<= 1) {
        unsigned v = (t >= d) ? sc[t - d] : 0u;
        __syncthreads();
        sc[t] += v;
        __syncthreads();
    }
    unsigned excl = sc[t] - v0;
    if (t < NB) { offs[t] = excl; gcur[t] = excl; }
    if (t == 0) offs[NB] = sc[NB - 1];
}

// ---- tile-local counting sort -> coalesced payload writes ----
__global__ __launch_bounds__(1024)
void scat_k(const void* ei, const float* ea, const unsigned* orw,
            unsigned* gcur, unsigned long long* pay, int E, int NB, int ntiles) {
    __shared__ unsigned long long lp[TILE];   // 96KB
    __shared__ unsigned lh[NBMAX];
    __shared__ unsigned lo[NBMAX + 1];
    __shared__ unsigned gb[NBMAX];
    const bool is64 = (*orw == 0u);
    const int* e32 = (const int*)ei;
    const long long* e64 = (const long long*)ei;
    const int t = threadIdx.x;

    for (int tile = blockIdx.x; tile < ntiles; tile += gridDim.x) {
        int base = tile * TILE;
        int tc = E - base; if (tc > TILE) tc = TILE;    // edges in this tile

        for (int i = t; i < NB; i += 1024) lh[i] = 0u;
        __syncthreads();

        int bn[EPT]; unsigned rk[EPT]; unsigned long long pv[EPT];
        #pragma unroll
        for (int i = 0; i < EPT; ++i) {
            int e = base + i * 1024 + t;
            bn[i] = -1;
            if (e < base + tc) {
                int c, r;
                if (is64) { c = (int)e64[E + e]; r = (int)e64[e]; }
                else      { c = e32[E + e];      r = e32[e]; }
                float w = ea[e];
                bn[i] = c >> 8;
                pv[i] = ((unsigned long long)__float_as_uint(w) << 32)
                        | ((unsigned)r << 8) | (unsigned)(c & 255);
                rk[i] = atomicAdd(&lh[bn[i]], 1u);
            }
        }
        __syncthreads();

        // inclusive scan of lh into lo
        unsigned v0 = (t < NB) ? lh[t] : 0u;
        lo[t] = v0;
        __syncthreads();
        for (int d = 1; d < 1024; d <<= 1) {
            unsigned v = (t >= d) ? lo[t - d] : 0u;
            __syncthreads();
            lo[t] += v;
            __syncthreads();
        }
        unsigned excl = lo[t] - v0;
        // reserve global range for each non-empty bin (one atomic per bin)
        if (t < NB && v0) gb[t] = atomicAdd(&gcur[t], v0);
        if (t < NB) lo[t] = excl;
        if (t == 0) lo[NB] = (unsigned)tc;
        __syncthreads();

        // place payloads into LDS, sorted by bin
        #pragma unroll
        for (int i = 0; i < EPT; ++i)
            if (bn[i] >= 0) lp[lo[bn[i]] + rk[i]] = pv[i];
        __syncthreads();

        // flush: linear LDS -> per-bin contiguous global runs (coalesced)
        for (int s = t; s < tc; s += 1024) {
            int a = 0, b = NB;                 // lo[a] <= s < lo[b]
            while (b - a > 1) {
                int m = (a + b) >> 1;
                if (lo[m] <= (unsigned)s) a = m; else b = m;
            }
            pay[(size_t)gb[a] + (unsigned)s - lo[a]] = lp[s];
        }
        __syncthreads();
    }
}

// ---- per-bin degree -> dis = rsqrt(1 + sum ew) ----
__global__ void degA_k(const unsigned long long* pay, const unsigned* offs,
                       float* dis, int N) {
    __shared__ float ld[BINSZ];
    int t = threadIdx.x, b = blockIdx.x;
    ld[t] = 0.f;
    __syncthreads();
    unsigned s = offs[b], e = offs[b + 1];
    for (unsigned j = s + t; j < e; j += BINSZ) {
        unsigned long long p = pay[j];
        atomicAdd(&ld[(unsigned)p & 255u], __uint_as_float((unsigned)(p >> 32)));
    }
    __syncthreads();
    int node = (b << 8) + t;
    if (node < N) {
        float d = 1.0f + ld[t];
        dis[node] = (d > 0.f) ? rsqrtf(d) : 0.f;
    }
}

// ---- per-bin aggregate (LDS, no global atomics) + 8->64 transform ----
__global__ __launch_bounds__(256)
void aggB_k(const unsigned long long* pay, const unsigned* offs,
            const float* dis, const float* x, const float* Wm, const float* bv,
            float* out, int N) {
    __shared__ float ag[8][BINSZ];            // [d][lc]: lc spreads banks
    int t = threadIdx.x, b = blockIdx.x;
    #pragma unroll
    for (int d = 0; d < 8; ++d) ag[d][t] = 0.f;
    __syncthreads();
    unsigned s = offs[b], e = offs[b + 1];
    for (unsigned j = s + t; j < e; j += BINSZ) {
        unsigned long long p = pay[j];
        unsigned lw = (unsigned)p;
        int lc = lw & 255u;
        int r = lw >> 8;
        float a = dis[r] * __uint_as_float((unsigned)(p >> 32));
        const float4* xr = (const float4*)(x + (size_t)r * 8);
        float4 u = xr[0], v = xr[1];
        atomicAdd(&ag[0][lc], a * u.x); atomicAdd(&ag[1][lc], a * u.y);
        atomicAdd(&ag[2][lc], a * u.z); atomicAdd(&ag[3][lc], a * u.w);
        atomicAdd(&ag[4][lc], a * v.x); atomicAdd(&ag[5][lc], a * v.y);
        atomicAdd(&ag[6][lc], a * v.z); atomicAdd(&ag[7][lc], a * v.w);
    }
    __syncthreads();
    // epilogue: wave per node row; out[c] = (dc*ag + dc^2*x[c]) @ W + b
    int lane = t & 63, wv = t >> 6;
    float wr[8];
    #pragma unroll
    for (int k = 0; k < 8; ++k) wr[k] = Wm[k * 64 + lane];
    float bj = bv[lane];
    int base = b << 8;
    for (int i = wv; i < BINSZ; i += 4) {
        int node = base + i;
        if (node >= N) break;
        float dc = dis[node];
        float acc = bj;
        #pragma unroll
        for (int k = 0; k < 8; ++k)
            acc += (dc * ag[k][i] + dc * dc * x[(size_t)node * 8 + k]) * wr[k];
        out[(size_t)node * 64 + lane] = acc;
    }
}

// ---------------- fallback (round-1 atomic path, ~3.7MB ws) ----------------
__global__ void fb_init_k(float* deg, float4* agg4, int N) {
    int i = blockIdx.x * blockDim.x + threadIdx.x, st = gridDim.x * blockDim.x;
    for (; i < N; i += st) {
        deg[i] = 1.0f;
        agg4[2 * i] = make_float4(0.f, 0.f, 0.f, 0.f);
        agg4[2 * i + 1] = make_float4(0.f, 0.f, 0.f, 0.f);
    }
}
__global__ void fb_deg_k(const void* ei, const float* ea, const unsigned* orw,
                         float* deg, int E) {
    const bool is64 = (*orw == 0u);
    const int* e32 = (const int*)ei;
    const long long* e64 = (const long long*)ei;
    int e = blockIdx.x * blockDim.x + threadIdx.x, st = gridDim.x * blockDim.x;
    for (; e < E; e += st) {
        int c = is64 ? (int)e64[E + e] : e32[E + e];
        atomicAdd(&deg[c], ea[e]);
    }
}
__global__ void fb_dis_k(float* deg, int N) {
    int i = blockIdx.x * blockDim.x + threadIdx.x, st = gridDim.x * blockDim.x;
    for (; i < N; i += st) {
        float d = deg[i];
        deg[i] = (d > 0.f) ? rsqrtf(d) : 0.f;
    }
}
__global__ void fb_edge_k(const void* ei, const float* ea, const unsigned* orw,
                          const float* dis, const float* x, float* agg, int E) {
    const bool is64 = (*orw == 0u);
    const int* e32 = (const int*)ei;
    const long long* e64 = (const long long*)ei;
    int e = blockIdx.x * blockDim.x + threadIdx.x, st = gridDim.x * blockDim.x;
    for (; e < E; e += st) {
        int r, c;
        if (is64) { r = (int)e64[e]; c = (int)e64[E + e]; }
        else      { r = e32[e];      c = e32[E + e]; }
        float nrm = dis[r] * ea[e] * dis[c];
        const float4* xr = (const float4*)(x + (size_t)r * 8);
        float4 a = xr[0], bb = xr[1];
        float* ag = agg + (size_t)c * 8;
        atomicAdd(ag + 0, nrm * a.x);  atomicAdd(ag + 1, nrm * a.y);
        atomicAdd(ag + 2, nrm * a.z);  atomicAdd(ag + 3, nrm * a.w);
        atomicAdd(ag + 4, nrm * bb.x); atomicAdd(ag + 5, nrm * bb.y);
        atomicAdd(ag + 6, nrm * bb.z); atomicAdd(ag + 7, nrm * bb.w);
    }
}
__global__ void fb_out_k(const float* x, const float* Wm, const float* bv,
                         const float* dis, const float* agg, float* out, int N) {
    int lane = threadIdx.x & 63;
    int wid = blockIdx.x * (blockDim.x >> 6) + (threadIdx.x >> 6);
    int nw = gridDim.x * (blockDim.x >> 6);
    float wr[8];
    #pragma unroll
    for (int k = 0; k < 8; ++k) wr[k] = Wm[k * 64 + lane];
    float bj = bv[lane];
    for (int i = wid; i < N; i += nw) {
        float d = dis[i];
        float ink = 0.f;
        if (lane < 8) ink = agg[(size_t)i * 8 + lane] + d * d * x[(size_t)i * 8 + lane];
        float acc = bj;
        #pragma unroll
        for (int k = 0; k < 8; ++k) acc += __shfl(ink, k) * wr[k];
        out[(size_t)i * 64 + lane] = acc;
    }
}

extern "C" void kernel_launch(void* const* d_in, const int* in_sizes, int n_in,
                              void* d_out, int out_size, void* d_ws, size_t ws_size,
                              hipStream_t stream) {
    const float* x  = (const float*)d_in[0];
    const void*  ei = d_in[1];
    const float* ea = (const float*)d_in[2];
    const float* Wm = (const float*)d_in[3];
    const float* bv = (const float*)d_in[4];
    float* out = (float*)d_out;

    const int N = in_sizes[0] / 8;
    const int E = in_sizes[2];
    const int NB = (N + BINSZ - 1) / BINSZ;

    char* ws = (char*)d_ws;
    size_t o = 0;
    unsigned* orw  = (unsigned*)(ws + o);  o += 256;
    unsigned* cnt  = (unsigned*)(ws + o);  o += ws_align(NBMAX * 4);
    unsigned* offs = (unsigned*)(ws + o);  o += ws_align((NBMAX + 1) * 4);
    unsigned* gcur = (unsigned*)(ws + o);  o += ws_align(NBMAX * 4);
    float* dis     = (float*)(ws + o);     o += ws_align((size_t)N * 4);
    unsigned long long* pay = (unsigned long long*)(ws + o);
    o += ws_align((size_t)E * 8);

    if (NB <= NBMAX && o <= ws_size && E >= 2048) {
        const int ntiles = (E + TILE - 1) / TILE;
        init_k<<<1, 256, 0, stream>>>((const unsigned*)ei, orw, cnt, NB, E);
        hist_k<<<256, 512, 0, stream>>>(ei, orw, cnt, E, NB);
        scan_k<<<1, 1024, 0, stream>>>(cnt, offs, gcur, NB);
        scat_k<<<ntiles, 1024, 0, stream>>>(ei, ea, orw, gcur, pay, E, NB, ntiles);
        degA_k<<<NB, BINSZ, 0, stream>>>(pay, offs, dis, N);
        aggB_k<<<NB, BINSZ, 0, stream>>>(pay, offs, dis, x, Wm, bv, out, N);
    } else {
        // fallback: simple atomic path
        float* agg = (float*)(ws + 256 + ws_align((size_t)N * 4));
        init_k<<<1, 256, 0, stream>>>((const unsigned*)ei, orw, cnt, 1, E);
        fb_init_k<<<(N + 255) / 256, 256, 0, stream>>>(dis, (float4*)agg, N);
        fb_deg_k<<<2048, 256, 0, stream>>>(ei, ea, orw, dis, E);
        fb_dis_k<<<(N + 255) / 256, 256, 0, stream>>>(dis, N);
        fb_edge_k<<<2048, 256, 0, stream>>>(ei, ea, orw, dis, x, agg, E);
        fb_out_k<<<2048, 256, 0, stream>>>(x, Wm, bv, dis, agg, out, N);
    }
}

// Round 5
// 260.850 us; speedup vs baseline: 6.0917x; 1.0610x over previous
//
#include <hip/hip_runtime.h>

// GCNConv(8->64), self-loops, symmetric norm.
// out[c] = ( dis[c] * sum_e dis[r]*ew*x[r]  +  dis[c]^2 * x[c] ) @ W + b
//
// Pipeline: bin histogram -> scan -> tile-local LDS counting sort (coalesced
// payload writes) -> SLICED per-bin deg partials -> rsqrt -> SLICED per-bin
// LDS aggregation writing non-atomic partials (S blocks per bin for latency
// hiding; round-4's single-block-per-bin aggB was occupancy-starved at
// 197us) -> reduce partials + fused 8->64 transform + bias.
//
// Payload pack (u64): ew_bits(32) | row(24) | lcol(8). Valid for N <= 2^24.

#define NBMAX 1024          // max bins => N <= 262144
#define BINSZ 256
#define TILE  12288         // edges per scatter tile (LDS: 96KB payload)
#define EPT   12            // TILE / 1024 threads

static inline size_t ws_align(size_t x) { return (x + 255) & ~(size_t)255; }

// ---- init: zero bin counters + detect int64-vs-int32 edge_index ----
__global__ void init_k(const unsigned* w, unsigned* orw, unsigned* cnt, int E) {
    int t = threadIdx.x;              // 256 threads, 1 block
    for (int i = t; i < NBMAX; i += 256) cnt[i] = 0u;
    __shared__ unsigned s;
    if (t == 0) s = 0u;
    __syncthreads();
    unsigned v = 0;
    int lim = (E < 2048) ? E : 2048;  // stay inside buffer even if int32
    for (int i = t; i < lim; i += 256)
        v |= w[2 * i + 1];            // odd words == 0 iff int64 layout
    atomicOr(&s, v);
    __syncthreads();
    if (t == 0) *orw = s;             // 0 => int64
}

// ---- histogram over destination bins ----
__global__ void hist_k(const void* ei, const unsigned* orw, unsigned* cnt,
                       int E, int NB) {
    __shared__ unsigned lh[NBMAX];
    const bool is64 = (*orw == 0u);
    const int* e32 = (const int*)ei;
    const long long* e64 = (const long long*)ei;
    for (int i = threadIdx.x; i < NB; i += blockDim.x) lh[i] = 0u;
    __syncthreads();
    int t = blockIdx.x * blockDim.x + threadIdx.x;
    int st = gridDim.x * blockDim.x;
    for (int e = t; e < E; e += st) {
        int c = is64 ? (int)e64[E + e] : e32[E + e];
        atomicAdd(&lh[c >> 8], 1u);
    }
    __syncthreads();
    for (int i = threadIdx.x; i < NB; i += blockDim.x) {
        unsigned v = lh[i];
        if (v) atomicAdd(&cnt[i], v);
    }
}

// ---- exclusive scan of cnt[NB] -> offs[NB+1], seed cursors ----
__global__ void scan_k(const unsigned* cnt, unsigned* offs, unsigned* gcur, int NB) {
    __shared__ unsigned sc[NBMAX];
    int t = threadIdx.x;              // 1024 threads, 1 block
    unsigned v0 = (t < NB) ? cnt[t] : 0u;
    sc[t] = v0;
    __syncthreads();
    for (int d = 1; d < 1024; d <<= 1) {
        unsigned v = (t >= d) ? sc[t - d] : 0u;
        __syncthreads();
        sc[t] += v;
        __syncthreads();
    }
    unsigned excl = sc[t] - v0;
    if (t < NB) { offs[t] = excl; gcur[t] = excl; }
    if (t == 0) offs[NB] = sc[NB - 1];
}

// ---- tile-local counting sort -> coalesced payload writes ----
__global__ __launch_bounds__(1024)
void scat_k(const void* ei, const float* ea, const unsigned* orw,
            unsigned* gcur, unsigned long long* pay, int E, int NB, int ntiles) {
    __shared__ unsigned long long lp[TILE];   // 96KB
    __shared__ unsigned lh[NBMAX];
    __shared__ unsigned lo[NBMAX + 1];
    __shared__ unsigned gb[NBMAX];
    const bool is64 = (*orw == 0u);
    const int* e32 = (const int*)ei;
    const long long* e64 = (const long long*)ei;
    const int t = threadIdx.x;

    for (int tile = blockIdx.x; tile < ntiles; tile += gridDim.x) {
        int base = tile * TILE;
        int tc = E - base; if (tc > TILE) tc = TILE;

        for (int i = t; i < NB; i += 1024) lh[i] = 0u;
        __syncthreads();

        int bn[EPT]; unsigned rk[EPT]; unsigned long long pv[EPT];
        #pragma unroll
        for (int i = 0; i < EPT; ++i) {
            int e = base + i * 1024 + t;
            bn[i] = -1;
            if (e < base + tc) {
                int c, r;
                if (is64) { c = (int)e64[E + e]; r = (int)e64[e]; }
                else      { c = e32[E + e];      r = e32[e]; }
                float w = ea[e];
                bn[i] = c >> 8;
                pv[i] = ((unsigned long long)__float_as_uint(w) << 32)
                        | ((unsigned)r << 8) | (unsigned)(c & 255);
                rk[i] = atomicAdd(&lh[bn[i]], 1u);
            }
        }
        __syncthreads();

        unsigned v0 = (t < NB) ? lh[t] : 0u;
        lo[t] = v0;
        __syncthreads();
        for (int d = 1; d < 1024; d <<= 1) {
            unsigned v = (t >= d) ? lo[t - d] : 0u;
            __syncthreads();
            lo[t] += v;
            __syncthreads();
        }
        unsigned excl = lo[t] - v0;
        if (t < NB && v0) gb[t] = atomicAdd(&gcur[t], v0);
        if (t < NB) lo[t] = excl;
        if (t == 0) lo[NB] = (unsigned)tc;
        __syncthreads();

        #pragma unroll
        for (int i = 0; i < EPT; ++i)
            if (bn[i] >= 0) lp[lo[bn[i]] + rk[i]] = pv[i];
        __syncthreads();

        for (int s = t; s < tc; s += 1024) {
            int a = 0, b = NB;
            while (b - a > 1) {
                int m = (a + b) >> 1;
                if (lo[m] <= (unsigned)s) a = m; else b = m;
            }
            pay[(size_t)gb[a] + (unsigned)s - lo[a]] = lp[s];
        }
        __syncthreads();
    }
}

// ---- sliced per-bin degree partials ----
__global__ void degS_k(const unsigned long long* pay, const unsigned* offs,
                       float* pdeg, int S) {
    __shared__ float ld[BINSZ];
    int b = blockIdx.x / S, s = blockIdx.x % S, t = threadIdx.x;
    ld[t] = 0.f;
    __syncthreads();
    unsigned s0 = offs[b], len = offs[b + 1] - s0;
    unsigned lo = s0 + (unsigned)((unsigned long long)len * s / S);
    unsigned hi = s0 + (unsigned)((unsigned long long)len * (s + 1) / S);
    for (unsigned j = lo + t; j < hi; j += BINSZ) {
        unsigned long long p = pay[j];
        atomicAdd(&ld[(unsigned)p & 255u], __uint_as_float((unsigned)(p >> 32)));
    }
    __syncthreads();
    pdeg[(size_t)blockIdx.x * BINSZ + t] = ld[t];
}

// ---- dis = rsqrt(1 + sum of partials) ----
__global__ void dis_k(const float* pdeg, float* dis, int N, int S) {
    int n = blockIdx.x * blockDim.x + threadIdx.x;
    int st = gridDim.x * blockDim.x;
    for (; n < N; n += st) {
        int b = n >> 8, lc = n & 255;
        float d = 1.0f;
        for (int s = 0; s < S; ++s)
            d += pdeg[((size_t)b * S + s) * BINSZ + lc];
        dis[n] = (d > 0.f) ? rsqrtf(d) : 0.f;
    }
}

// ---- sliced per-bin LDS aggregation -> non-atomic partial writes ----
__global__ __launch_bounds__(256)
void aggS_k(const unsigned long long* pay, const unsigned* offs,
            const float* dis, const float* x, float* partial, int S) {
    __shared__ float ag[8][BINSZ];
    int b = blockIdx.x / S, s = blockIdx.x % S, t = threadIdx.x;
    #pragma unroll
    for (int d = 0; d < 8; ++d) ag[d][t] = 0.f;
    __syncthreads();
    unsigned s0 = offs[b], len = offs[b + 1] - s0;
    unsigned lo = s0 + (unsigned)((unsigned long long)len * s / S);
    unsigned hi = s0 + (unsigned)((unsigned long long)len * (s + 1) / S);
    for (unsigned j = lo + t; j < hi; j += BINSZ) {
        unsigned long long p = pay[j];
        unsigned lw = (unsigned)p;
        int lc = lw & 255u;
        int r = lw >> 8;
        float a = dis[r] * __uint_as_float((unsigned)(p >> 32));
        const float4* xr = (const float4*)(x + (size_t)r * 8);
        float4 u = xr[0], v = xr[1];
        atomicAdd(&ag[0][lc], a * u.x); atomicAdd(&ag[1][lc], a * u.y);
        atomicAdd(&ag[2][lc], a * u.z); atomicAdd(&ag[3][lc], a * u.w);
        atomicAdd(&ag[4][lc], a * v.x); atomicAdd(&ag[5][lc], a * v.y);
        atomicAdd(&ag[6][lc], a * v.z); atomicAdd(&ag[7][lc], a * v.w);
    }
    __syncthreads();
    float* dst = partial + (size_t)blockIdx.x * (8 * BINSZ);
    #pragma unroll
    for (int d = 0; d < 8; ++d) dst[d * BINSZ + t] = ag[d][t];
}

// ---- reduce partials + fused 8->64 transform + self-loop + bias ----
__global__ __launch_bounds__(256)
void red_k(const float* partial, const float* dis, const float* x,
           const float* Wm, const float* bv, float* out, int N, int S) {
    __shared__ float ag[8][BINSZ];
    int b = blockIdx.x, t = threadIdx.x;
    float acc[8];
    #pragma unroll
    for (int d = 0; d < 8; ++d) acc[d] = 0.f;
    for (int s = 0; s < S; ++s) {
        const float* src = partial + ((size_t)b * S + s) * (8 * BINSZ);
        #pragma unroll
        for (int d = 0; d < 8; ++d) acc[d] += src[d * BINSZ + t];
    }
    #pragma unroll
    for (int d = 0; d < 8; ++d) ag[d][t] = acc[d];
    __syncthreads();
    int lane = t & 63, wv = t >> 6;
    float wr[8];
    #pragma unroll
    for (int k = 0; k < 8; ++k) wr[k] = Wm[k * 64 + lane];
    float bj = bv[lane];
    int base = b << 8;
    for (int i = wv; i < BINSZ; i += 4) {
        int node = base + i;
        if (node >= N) break;
        float dc = dis[node];
        float a2 = bj;
        #pragma unroll
        for (int k = 0; k < 8; ++k)
            a2 += (dc * ag[k][i] + dc * dc * x[(size_t)node * 8 + k]) * wr[k];
        out[(size_t)node * 64 + lane] = a2;
    }
}

// ---------------- fallback (round-1 atomic path, ~3.7MB ws) ----------------
__global__ void fb_init_k(float* deg, float4* agg4, int N) {
    int i = blockIdx.x * blockDim.x + threadIdx.x, st = gridDim.x * blockDim.x;
    for (; i < N; i += st) {
        deg[i] = 1.0f;
        agg4[2 * i] = make_float4(0.f, 0.f, 0.f, 0.f);
        agg4[2 * i + 1] = make_float4(0.f, 0.f, 0.f, 0.f);
    }
}
__global__ void fb_deg_k(const void* ei, const float* ea, const unsigned* orw,
                         float* deg, int E) {
    const bool is64 = (*orw == 0u);
    const int* e32 = (const int*)ei;
    const long long* e64 = (const long long*)ei;
    int e = blockIdx.x * blockDim.x + threadIdx.x, st = gridDim.x * blockDim.x;
    for (; e < E; e += st) {
        int c = is64 ? (int)e64[E + e] : e32[E + e];
        atomicAdd(&deg[c], ea[e]);
    }
}
__global__ void fb_dis_k(float* deg, int N) {
    int i = blockIdx.x * blockDim.x + threadIdx.x, st = gridDim.x * blockDim.x;
    for (; i < N; i += st) {
        float d = deg[i];
        deg[i] = (d > 0.f) ? rsqrtf(d) : 0.f;
    }
}
__global__ void fb_edge_k(const void* ei, const float* ea, const unsigned* orw,
                          const float* dis, const float* x, float* agg, int E) {
    const bool is64 = (*orw == 0u);
    const int* e32 = (const int*)ei;
    const long long* e64 = (const long long*)ei;
    int e = blockIdx.x * blockDim.x + threadIdx.x, st = gridDim.x * blockDim.x;
    for (; e < E; e += st) {
        int r, c;
        if (is64) { r = (int)e64[e]; c = (int)e64[E + e]; }
        else      { r = e32[e];      c = e32[E + e]; }
        float nrm = dis[r] * ea[e] * dis[c];
        const float4* xr = (const float4*)(x + (size_t)r * 8);
        float4 a = xr[0], bb = xr[1];
        float* ag = agg + (size_t)c * 8;
        atomicAdd(ag + 0, nrm * a.x);  atomicAdd(ag + 1, nrm * a.y);
        atomicAdd(ag + 2, nrm * a.z);  atomicAdd(ag + 3, nrm * a.w);
        atomicAdd(ag + 4, nrm * bb.x); atomicAdd(ag + 5, nrm * bb.y);
        atomicAdd(ag + 6, nrm * bb.z); atomicAdd(ag + 7, nrm * bb.w);
    }
}
__global__ void fb_out_k(const float* x, const float* Wm, const float* bv,
                         const float* dis, const float* agg, float* out, int N) {
    int lane = threadIdx.x & 63;
    int wid = blockIdx.x * (blockDim.x >> 6) + (threadIdx.x >> 6);
    int nw = gridDim.x * (blockDim.x >> 6);
    float wr[8];
    #pragma unroll
    for (int k = 0; k < 8; ++k) wr[k] = Wm[k * 64 + lane];
    float bj = bv[lane];
    for (int i = wid; i < N; i += nw) {
        float d = dis[i];
        float ink = 0.f;
        if (lane < 8) ink = agg[(size_t)i * 8 + lane] + d * d * x[(size_t)i * 8 + lane];
        float acc = bj;
        #pragma unroll
        for (int k = 0; k < 8; ++k) acc += __shfl(ink, k) * wr[k];
        out[(size_t)i * 64 + lane] = acc;
    }
}

extern "C" void kernel_launch(void* const* d_in, const int* in_sizes, int n_in,
                              void* d_out, int out_size, void* d_ws, size_t ws_size,
                              hipStream_t stream) {
    const float* x  = (const float*)d_in[0];
    const void*  ei = d_in[1];
    const float* ea = (const float*)d_in[2];
    const float* Wm = (const float*)d_in[3];
    const float* bv = (const float*)d_in[4];
    float* out = (float*)d_out;

    const int N = in_sizes[0] / 8;
    const int E = in_sizes[2];
    const int NB = (N + BINSZ - 1) / BINSZ;

    char* ws = (char*)d_ws;
    size_t o = 0;
    unsigned* orw  = (unsigned*)(ws + o);  o += 256;
    unsigned* cnt  = (unsigned*)(ws + o);  o += ws_align(NBMAX * 4);
    unsigned* offs = (unsigned*)(ws + o);  o += ws_align((NBMAX + 1) * 4);
    unsigned* gcur = (unsigned*)(ws + o);  o += ws_align(NBMAX * 4);
    float* dis     = (float*)(ws + o);     o += ws_align((size_t)N * 4);
    unsigned long long* pay = (unsigned long long*)(ws + o);
    o += ws_align((size_t)E * 8);
    // partial/pdeg union region (pdeg used before aggS, partial after)
    float* partial = (float*)(ws + o);

    // pick largest slice factor whose partial buffer fits the workspace
    int S = 0;
    for (int cand = 8; cand >= 1; cand >>= 1) {
        size_t need = o + ws_align((size_t)NB * cand * 8 * BINSZ * 4);
        if (need <= ws_size) { S = cand; break; }
    }

    if (NB <= NBMAX && S > 0 && E >= 2048) {
        const int ntiles = (E + TILE - 1) / TILE;
        init_k<<<1, 256, 0, stream>>>((const unsigned*)ei, orw, cnt, E);
        hist_k<<<256, 512, 0, stream>>>(ei, orw, cnt, E, NB);
        scan_k<<<1, 1024, 0, stream>>>(cnt, offs, gcur, NB);
        scat_k<<<ntiles, 1024, 0, stream>>>(ei, ea, orw, gcur, pay, E, NB, ntiles);
        degS_k<<<NB * S, BINSZ, 0, stream>>>(pay, offs, partial, S);
        dis_k<<<(N + 255) / 256, 256, 0, stream>>>(partial, dis, N, S);
        aggS_k<<<NB * S, BINSZ, 0, stream>>>(pay, offs, dis, x, partial, S);
        red_k<<<NB, BINSZ, 0, stream>>>(partial, dis, x, Wm, bv, out, N, S);
    } else {
        float* agg = (float*)(ws + 256 + ws_align((size_t)N * 4));
        init_k<<<1, 256, 0, stream>>>((const unsigned*)ei, orw, cnt, E);
        fb_init_k<<<(N + 255) / 256, 256, 0, stream>>>(dis, (float4*)agg, N);
        fb_deg_k<<<2048, 256, 0, stream>>>(ei, ea, orw, dis, E);
        fb_dis_k<<<(N + 255) / 256, 256, 0, stream>>>(dis, N);
        fb_edge_k<<<2048, 256, 0, stream>>>(ei, ea, orw, dis, x, agg, E);
        fb_out_k<<<2048, 256, 0, stream>>>(x, Wm, bv, dis, agg, out, N);
    }
}

// Round 6
// 157.697 us; speedup vs baseline: 10.0765x; 1.6541x over previous
//
#include <hip/hip_runtime.h>

// GCNConv(8->64), self-loops, symmetric norm.
// out[c] = ( dis[c] * sum_e dis[r]*ew*x[r]  +  dis[c]^2 * x[c] ) @ W + b
//
// v6: full counting sort to per-node CSR, zero-atomic aggregation.
//   hist(bin256) -> scan -> scat (tile LDS sort by bin, coalesced) ->
//   sort2 (per-bin LDS sort by node, fused deg/rsqrt/noffs) ->
//   agg (wave per node: contiguous payload run, register accumulate,
//        shfl_xor reduce, fused 8->64 transform + self-loop + bias).
// Replaces round-5's aggS (144us = 204.8M LDS atomics @ ~2.3/cy/CU ceiling)
// with 9.6M LDS atomics total + register math.
//
// Payload pack (u64): ew_bits(32) | row(24) | lcol(8). Valid for N <= 2^24.

#define NBMAX 1024          // max bins => N <= 262144
#define BINSZ 256
#define TILE  12288         // edges per scatter tile (LDS: 96KB payload)
#define EPT   12            // TILE / 1024 threads
#define CAP   12288         // max edges per bin staged in LDS by sort2

static inline size_t ws_align(size_t x) { return (x + 255) & ~(size_t)255; }

// ---- init: zero bin counters + detect int64-vs-int32 edge_index ----
__global__ void init_k(const unsigned* w, unsigned* orw, unsigned* cnt, int E) {
    int t = threadIdx.x;              // 256 threads, 1 block
    for (int i = t; i < NBMAX; i += 256) cnt[i] = 0u;
    __shared__ unsigned s;
    if (t == 0) s = 0u;
    __syncthreads();
    unsigned v = 0;
    int lim = (E < 2048) ? E : 2048;  // stay inside buffer even if int32
    for (int i = t; i < lim; i += 256)
        v |= w[2 * i + 1];            // odd words == 0 iff int64 layout
    atomicOr(&s, v);
    __syncthreads();
    if (t == 0) *orw = s;             // 0 => int64
}

// ---- histogram over destination bins ----
__global__ void hist_k(const void* ei, const unsigned* orw, unsigned* cnt,
                       int E, int NB) {
    __shared__ unsigned lh[NBMAX];
    const bool is64 = (*orw == 0u);
    const int* e32 = (const int*)ei;
    const long long* e64 = (const long long*)ei;
    for (int i = threadIdx.x; i < NB; i += blockDim.x) lh[i] = 0u;
    __syncthreads();
    int t = blockIdx.x * blockDim.x + threadIdx.x;
    int st = gridDim.x * blockDim.x;
    for (int e = t; e < E; e += st) {
        int c = is64 ? (int)e64[E + e] : e32[E + e];
        atomicAdd(&lh[c >> 8], 1u);
    }
    __syncthreads();
    for (int i = threadIdx.x; i < NB; i += blockDim.x) {
        unsigned v = lh[i];
        if (v) atomicAdd(&cnt[i], v);
    }
}

// ---- exclusive scan of cnt[NB] -> offs[NB+1], seed cursors ----
__global__ void scan_k(const unsigned* cnt, unsigned* offs, unsigned* gcur, int NB) {
    __shared__ unsigned sc[NBMAX];
    int t = threadIdx.x;              // 1024 threads, 1 block
    unsigned v0 = (t < NB) ? cnt[t] : 0u;
    sc[t] = v0;
    __syncthreads();
    for (int d = 1; d < 1024; d <<= 1) {
        unsigned v = (t >= d) ? sc[t - d] : 0u;
        __syncthreads();
        sc[t] += v;
        __syncthreads();
    }
    unsigned excl = sc[t] - v0;
    if (t < NB) { offs[t] = excl; gcur[t] = excl; }
    if (t == 0) offs[NB] = sc[NB - 1];
}

// ---- tile-local counting sort -> coalesced payload writes (by bin) ----
__global__ __launch_bounds__(1024)
void scat_k(const void* ei, const float* ea, const unsigned* orw,
            unsigned* gcur, unsigned long long* pay, int E, int NB, int ntiles) {
    __shared__ unsigned long long lp[TILE];   // 96KB
    __shared__ unsigned lh[NBMAX];
    __shared__ unsigned lo[NBMAX + 1];
    __shared__ unsigned gb[NBMAX];
    const bool is64 = (*orw == 0u);
    const int* e32 = (const int*)ei;
    const long long* e64 = (const long long*)ei;
    const int t = threadIdx.x;

    for (int tile = blockIdx.x; tile < ntiles; tile += gridDim.x) {
        int base = tile * TILE;
        int tc = E - base; if (tc > TILE) tc = TILE;

        for (int i = t; i < NB; i += 1024) lh[i] = 0u;
        __syncthreads();

        int bn[EPT]; unsigned rk[EPT]; unsigned long long pv[EPT];
        #pragma unroll
        for (int i = 0; i < EPT; ++i) {
            int e = base + i * 1024 + t;
            bn[i] = -1;
            if (e < base + tc) {
                int c, r;
                if (is64) { c = (int)e64[E + e]; r = (int)e64[e]; }
                else      { c = e32[E + e];      r = e32[e]; }
                float w = ea[e];
                bn[i] = c >> 8;
                pv[i] = ((unsigned long long)__float_as_uint(w) << 32)
                        | ((unsigned)r << 8) | (unsigned)(c & 255);
                rk[i] = atomicAdd(&lh[bn[i]], 1u);
            }
        }
        __syncthreads();

        unsigned v0 = (t < NB) ? lh[t] : 0u;
        lo[t] = v0;
        __syncthreads();
        for (int d = 1; d < 1024; d <<= 1) {
            unsigned v = (t >= d) ? lo[t - d] : 0u;
            __syncthreads();
            lo[t] += v;
            __syncthreads();
        }
        unsigned excl = lo[t] - v0;
        if (t < NB && v0) gb[t] = atomicAdd(&gcur[t], v0);
        if (t < NB) lo[t] = excl;
        if (t == 0) lo[NB] = (unsigned)tc;
        __syncthreads();

        #pragma unroll
        for (int i = 0; i < EPT; ++i)
            if (bn[i] >= 0) lp[lo[bn[i]] + rk[i]] = pv[i];
        __syncthreads();

        for (int s = t; s < tc; s += 1024) {
            int a = 0, b = NB;
            while (b - a > 1) {
                int m = (a + b) >> 1;
                if (lo[m] <= (unsigned)s) a = m; else b = m;
            }
            pay[(size_t)gb[a] + (unsigned)s - lo[a]] = lp[s];
        }
        __syncthreads();
    }
}

// ---- per-bin counting sort by node + deg/rsqrt + per-node offsets ----
__global__ __launch_bounds__(1024)
void sort2_k(const unsigned long long* pay, const unsigned* offs,
             unsigned long long* pay2, unsigned* noffs, float* dis,
             int N, int NB, int E) {
    __shared__ unsigned long long lp[CAP];    // 96KB sorted staging
    __shared__ unsigned cnt[BINSZ];
    __shared__ unsigned loc[BINSZ];
    __shared__ unsigned cur[BINSZ];
    __shared__ float dw[BINSZ];
    int b = blockIdx.x, t = threadIdx.x;
    if (t < BINSZ) { cnt[t] = 0u; dw[t] = 0.f; }
    if (b == 0 && t == 0) noffs[N] = (unsigned)E;
    __syncthreads();
    unsigned base = offs[b], len = offs[b + 1] - base;
    // pass 1: count + weighted degree
    for (unsigned j = t; j < len; j += 1024) {
        unsigned long long p = pay[base + j];
        unsigned lc = (unsigned)p & 255u;
        atomicAdd(&cnt[lc], 1u);
        atomicAdd(&dw[lc], __uint_as_float((unsigned)(p >> 32)));
    }
    __syncthreads();
    // inclusive scan cnt -> loc (256 wide)
    if (t < BINSZ) loc[t] = cnt[t];
    __syncthreads();
    for (int d = 1; d < BINSZ; d <<= 1) {
        unsigned v = 0;
        if (t < BINSZ && t >= d) v = loc[t - d];
        __syncthreads();
        if (t < BINSZ && t >= d) loc[t] += v;
        __syncthreads();
    }
    if (t < BINSZ) {
        unsigned excl = loc[t] - cnt[t];
        cur[t] = excl;
        int node = (b << 8) + t;
        if (node < N) {
            noffs[node] = base + excl;
            float d = 1.0f + dw[t];
            dis[node] = (d > 0.f) ? rsqrtf(d) : 0.f;
        }
    }
    __syncthreads();
    // pass 2: rank + place (LDS for pos<CAP, direct global for rare overflow)
    for (unsigned j = t; j < len; j += 1024) {
        unsigned long long p = pay[base + j];
        unsigned lc = (unsigned)p & 255u;
        unsigned pos = atomicAdd(&cur[lc], 1u);
        if (pos < CAP) lp[pos] = p;
        else pay2[(size_t)base + pos] = p;
    }
    __syncthreads();
    unsigned m = len < CAP ? len : CAP;
    for (unsigned j = t; j < m; j += 1024)
        pay2[(size_t)base + j] = lp[j];
}

// ---- wave-per-node CSR aggregate + fused 8->64 transform + bias ----
__global__ __launch_bounds__(256)
void agg_k(const unsigned long long* pay2, const unsigned* noffs,
           const float* dis, const float* x, const float* Wm, const float* bv,
           float* out, int N) {
    __shared__ float ag[4][8];
    int t = threadIdx.x;
    int wv = t >> 6, lane = t & 63;
    int slot = lane >> 3, d = lane & 7;
    int node = blockIdx.x * 4 + wv;
    float wr[8];
    #pragma unroll
    for (int k = 0; k < 8; ++k) wr[k] = Wm[k * 64 + lane];
    float o2 = bv[lane];
    float acc = 0.f;
    if (node < N) {
        unsigned s = noffs[node], e = noffs[node + 1];
        for (unsigned j = s + slot; j < e; j += 8) {
            unsigned long long p = pay2[j];
            unsigned r = ((unsigned)p >> 8) & 0xFFFFFFu;
            float a = dis[r] * __uint_as_float((unsigned)(p >> 32));
            acc += a * x[(size_t)r * 8 + d];
        }
    }
    acc += __shfl_xor(acc, 8);
    acc += __shfl_xor(acc, 16);
    acc += __shfl_xor(acc, 32);
    if (node < N && slot == 0) {
        float dc = dis[node];
        ag[wv][d] = dc * acc + dc * dc * x[(size_t)node * 8 + d];
    }
    __syncthreads();
    if (node < N) {
        #pragma unroll
        for (int k = 0; k < 8; ++k) o2 += ag[wv][k] * wr[k];
        out[(size_t)node * 64 + lane] = o2;
    }
}

// ---------------- r5 fallback: sliced LDS-atomic aggregation ----------------
__global__ void degS_k(const unsigned long long* pay, const unsigned* offs,
                       float* pdeg, int S) {
    __shared__ float ld[BINSZ];
    int b = blockIdx.x / S, s = blockIdx.x % S, t = threadIdx.x;
    ld[t] = 0.f;
    __syncthreads();
    unsigned s0 = offs[b], len = offs[b + 1] - s0;
    unsigned lo = s0 + (unsigned)((unsigned long long)len * s / S);
    unsigned hi = s0 + (unsigned)((unsigned long long)len * (s + 1) / S);
    for (unsigned j = lo + t; j < hi; j += BINSZ) {
        unsigned long long p = pay[j];
        atomicAdd(&ld[(unsigned)p & 255u], __uint_as_float((unsigned)(p >> 32)));
    }
    __syncthreads();
    pdeg[(size_t)blockIdx.x * BINSZ + t] = ld[t];
}

__global__ void disP_k(const float* pdeg, float* dis, int N, int S) {
    int n = blockIdx.x * blockDim.x + threadIdx.x;
    int st = gridDim.x * blockDim.x;
    for (; n < N; n += st) {
        int b = n >> 8, lc = n & 255;
        float d = 1.0f;
        for (int s = 0; s < S; ++s)
            d += pdeg[((size_t)b * S + s) * BINSZ + lc];
        dis[n] = (d > 0.f) ? rsqrtf(d) : 0.f;
    }
}

__global__ __launch_bounds__(256)
void aggS_k(const unsigned long long* pay, const unsigned* offs,
            const float* dis, const float* x, float* partial, int S) {
    __shared__ float ag[8][BINSZ];
    int b = blockIdx.x / S, s = blockIdx.x % S, t = threadIdx.x;
    #pragma unroll
    for (int d = 0; d < 8; ++d) ag[d][t] = 0.f;
    __syncthreads();
    unsigned s0 = offs[b], len = offs[b + 1] - s0;
    unsigned lo = s0 + (unsigned)((unsigned long long)len * s / S);
    unsigned hi = s0 + (unsigned)((unsigned long long)len * (s + 1) / S);
    for (unsigned j = lo + t; j < hi; j += BINSZ) {
        unsigned long long p = pay[j];
        unsigned lw = (unsigned)p;
        int lc = lw & 255u;
        int r = lw >> 8;
        float a = dis[r] * __uint_as_float((unsigned)(p >> 32));
        const float4* xr = (const float4*)(x + (size_t)r * 8);
        float4 u = xr[0], v = xr[1];
        atomicAdd(&ag[0][lc], a * u.x); atomicAdd(&ag[1][lc], a * u.y);
        atomicAdd(&ag[2][lc], a * u.z); atomicAdd(&ag[3][lc], a * u.w);
        atomicAdd(&ag[4][lc], a * v.x); atomicAdd(&ag[5][lc], a * v.y);
        atomicAdd(&ag[6][lc], a * v.z); atomicAdd(&ag[7][lc], a * v.w);
    }
    __syncthreads();
    float* dst = partial + (size_t)blockIdx.x * (8 * BINSZ);
    #pragma unroll
    for (int d = 0; d < 8; ++d) dst[d * BINSZ + t] = ag[d][t];
}

__global__ __launch_bounds__(256)
void red_k(const float* partial, const float* dis, const float* x,
           const float* Wm, const float* bv, float* out, int N, int S) {
    __shared__ float ag[8][BINSZ];
    int b = blockIdx.x, t = threadIdx.x;
    float acc[8];
    #pragma unroll
    for (int d = 0; d < 8; ++d) acc[d] = 0.f;
    for (int s = 0; s < S; ++s) {
        const float* src = partial + ((size_t)b * S + s) * (8 * BINSZ);
        #pragma unroll
        for (int d = 0; d < 8; ++d) acc[d] += src[d * BINSZ + t];
    }
    #pragma unroll
    for (int d = 0; d < 8; ++d) ag[d][t] = acc[d];
    __syncthreads();
    int lane = t & 63, wv = t >> 6;
    float wr[8];
    #pragma unroll
    for (int k = 0; k < 8; ++k) wr[k] = Wm[k * 64 + lane];
    float bj = bv[lane];
    int base = b << 8;
    for (int i = wv; i < BINSZ; i += 4) {
        int node = base + i;
        if (node >= N) break;
        float dc = dis[node];
        float a2 = bj;
        #pragma unroll
        for (int k = 0; k < 8; ++k)
            a2 += (dc * ag[k][i] + dc * dc * x[(size_t)node * 8 + k]) * wr[k];
        out[(size_t)node * 64 + lane] = a2;
    }
}

// ---------------- round-1 fallback (tiny ws) ----------------
__global__ void fb_init_k(float* deg, float4* agg4, int N) {
    int i = blockIdx.x * blockDim.x + threadIdx.x, st = gridDim.x * blockDim.x;
    for (; i < N; i += st) {
        deg[i] = 1.0f;
        agg4[2 * i] = make_float4(0.f, 0.f, 0.f, 0.f);
        agg4[2 * i + 1] = make_float4(0.f, 0.f, 0.f, 0.f);
    }
}
__global__ void fb_deg_k(const void* ei, const float* ea, const unsigned* orw,
                         float* deg, int E) {
    const bool is64 = (*orw == 0u);
    const int* e32 = (const int*)ei;
    const long long* e64 = (const long long*)ei;
    int e = blockIdx.x * blockDim.x + threadIdx.x, st = gridDim.x * blockDim.x;
    for (; e < E; e += st) {
        int c = is64 ? (int)e64[E + e] : e32[E + e];
        atomicAdd(&deg[c], ea[e]);
    }
}
__global__ void fb_dis_k(float* deg, int N) {
    int i = blockIdx.x * blockDim.x + threadIdx.x, st = gridDim.x * blockDim.x;
    for (; i < N; i += st) {
        float d = deg[i];
        deg[i] = (d > 0.f) ? rsqrtf(d) : 0.f;
    }
}
__global__ void fb_edge_k(const void* ei, const float* ea, const unsigned* orw,
                          const float* dis, const float* x, float* agg, int E) {
    const bool is64 = (*orw == 0u);
    const int* e32 = (const int*)ei;
    const long long* e64 = (const long long*)ei;
    int e = blockIdx.x * blockDim.x + threadIdx.x, st = gridDim.x * blockDim.x;
    for (; e < E; e += st) {
        int r, c;
        if (is64) { r = (int)e64[e]; c = (int)e64[E + e]; }
        else      { r = e32[e];      c = e32[E + e]; }
        float nrm = dis[r] * ea[e] * dis[c];
        const float4* xr = (const float4*)(x + (size_t)r * 8);
        float4 a = xr[0], bb = xr[1];
        float* ag = agg + (size_t)c * 8;
        atomicAdd(ag + 0, nrm * a.x);  atomicAdd(ag + 1, nrm * a.y);
        atomicAdd(ag + 2, nrm * a.z);  atomicAdd(ag + 3, nrm * a.w);
        atomicAdd(ag + 4, nrm * bb.x); atomicAdd(ag + 5, nrm * bb.y);
        atomicAdd(ag + 6, nrm * bb.z); atomicAdd(ag + 7, nrm * bb.w);
    }
}
__global__ void fb_out_k(const float* x, const float* Wm, const float* bv,
                         const float* dis, const float* agg, float* out, int N) {
    int lane = threadIdx.x & 63;
    int wid = blockIdx.x * (blockDim.x >> 6) + (threadIdx.x >> 6);
    int nw = gridDim.x * (blockDim.x >> 6);
    float wr[8];
    #pragma unroll
    for (int k = 0; k < 8; ++k) wr[k] = Wm[k * 64 + lane];
    float bj = bv[lane];
    for (int i = wid; i < N; i += nw) {
        float d = dis[i];
        float ink = 0.f;
        if (lane < 8) ink = agg[(size_t)i * 8 + lane] + d * d * x[(size_t)i * 8 + lane];
        float acc = bj;
        #pragma unroll
        for (int k = 0; k < 8; ++k) acc += __shfl(ink, k) * wr[k];
        out[(size_t)i * 64 + lane] = acc;
    }
}

extern "C" void kernel_launch(void* const* d_in, const int* in_sizes, int n_in,
                              void* d_out, int out_size, void* d_ws, size_t ws_size,
                              hipStream_t stream) {
    const float* x  = (const float*)d_in[0];
    const void*  ei = d_in[1];
    const float* ea = (const float*)d_in[2];
    const float* Wm = (const float*)d_in[3];
    const float* bv = (const float*)d_in[4];
    float* out = (float*)d_out;

    const int N = in_sizes[0] / 8;
    const int E = in_sizes[2];
    const int NB = (N + BINSZ - 1) / BINSZ;

    char* ws = (char*)d_ws;
    size_t o = 0;
    unsigned* orw   = (unsigned*)(ws + o); o += 256;
    unsigned* cnt   = (unsigned*)(ws + o); o += ws_align(NBMAX * 4);
    unsigned* offs  = (unsigned*)(ws + o); o += ws_align((NBMAX + 1) * 4);
    unsigned* gcur  = (unsigned*)(ws + o); o += ws_align(NBMAX * 4);
    float* dis      = (float*)(ws + o);    o += ws_align((size_t)N * 4);
    unsigned* noffs = (unsigned*)(ws + o); o += ws_align((size_t)(N + 1) * 4);
    unsigned long long* pay = (unsigned long long*)(ws + o);
    o += ws_align((size_t)E * 8);
    // pay2 (v6) / partial (r5 fallback) share this region
    char* tail = ws + o;

    const int ntiles = (E + TILE - 1) / TILE;

    if (NB <= NBMAX && E >= 2048 && o + ws_align((size_t)E * 8) <= ws_size) {
        // ---- v6: full sort -> CSR -> zero-atomic aggregate ----
        unsigned long long* pay2 = (unsigned long long*)tail;
        init_k<<<1, 256, 0, stream>>>((const unsigned*)ei, orw, cnt, E);
        hist_k<<<256, 512, 0, stream>>>(ei, orw, cnt, E, NB);
        scan_k<<<1, 1024, 0, stream>>>(cnt, offs, gcur, NB);
        scat_k<<<ntiles, 1024, 0, stream>>>(ei, ea, orw, gcur, pay, E, NB, ntiles);
        sort2_k<<<NB, 1024, 0, stream>>>(pay, offs, pay2, noffs, dis, N, NB, E);
        agg_k<<<(N + 3) / 4, 256, 0, stream>>>(pay2, noffs, dis, x, Wm, bv, out, N);
        return;
    }

    // ---- r5 fallback: sliced LDS-atomic aggregation ----
    int S = 0;
    for (int cand = 8; cand >= 1; cand >>= 1) {
        size_t need = o + ws_align((size_t)NB * cand * 8 * BINSZ * 4);
        if (need <= ws_size) { S = cand; break; }
    }
    if (NB <= NBMAX && S > 0 && E >= 2048) {
        float* partial = (float*)tail;
        init_k<<<1, 256, 0, stream>>>((const unsigned*)ei, orw, cnt, E);
        hist_k<<<256, 512, 0, stream>>>(ei, orw, cnt, E, NB);
        scan_k<<<1, 1024, 0, stream>>>(cnt, offs, gcur, NB);
        scat_k<<<ntiles, 1024, 0, stream>>>(ei, ea, orw, gcur, pay, E, NB, ntiles);
        degS_k<<<NB * S, BINSZ, 0, stream>>>(pay, offs, partial, S);
        disP_k<<<(N + 255) / 256, 256, 0, stream>>>(partial, dis, N, S);
        aggS_k<<<NB * S, BINSZ, 0, stream>>>(pay, offs, dis, x, partial, S);
        red_k<<<NB, BINSZ, 0, stream>>>(partial, dis, x, Wm, bv, out, N, S);
    } else {
        float* agg = (float*)(ws + 256 + ws_align((size_t)N * 4));
        init_k<<<1, 256, 0, stream>>>((const unsigned*)ei, orw, cnt, E);
        fb_init_k<<<(N + 255) / 256, 256, 0, stream>>>(dis, (float4*)agg, N);
        fb_deg_k<<<2048, 256, 0, stream>>>(ei, ea, orw, dis, E);
        fb_dis_k<<<(N + 255) / 256, 256, 0, stream>>>(dis, N);
        fb_edge_k<<<2048, 256, 0, stream>>>(ei, ea, orw, dis, x, agg, E);
        fb_out_k<<<2048, 256, 0, stream>>>(x, Wm, bv, dis, agg, out, N);
    }
}

// Round 7
// 142.824 us; speedup vs baseline: 11.1258x; 1.1041x over previous
//
#include <hip/hip_runtime.h>

// GCNConv(8->64), self-loops, symmetric norm.
// out[c] = ( dis[c] * sum_e dis[r]*ew*x[r]  +  dis[c]^2 * x[c] ) @ W + b
//
// v7: v6 pipeline (hist -> scan -> tile-LDS bin sort -> per-bin node sort ->
// wave-per-node CSR aggregate) with:
//   * scat TILE 12288->6144: 60KB LDS => 2 blocks/CU (was 1, occupancy cap)
//   * agg: 16 slots x 4 float2 dim-pairs + dual-stream unroll => 4x MLP on
//     the pay2 -> {dis,x} dependent-gather chain (r6: 63us @ 15% HBM / 26%
//     VALU = latency-bound, 4 sequential rounds with 8 slots)
//
// Payload pack (u64): ew_bits(32) | row(24) | lcol(8). Valid for N <= 2^24.

#define NBMAX 1024          // max bins => N <= 262144
#define BINSZ 256
#define TILE  6144          // edges per scatter tile (LDS: 48KB payload)
#define EPT   6             // TILE / 1024 threads
#define CAP   12288         // max edges per bin staged in LDS by sort2

static inline size_t ws_align(size_t x) { return (x + 255) & ~(size_t)255; }

// ---- init: zero bin counters + detect int64-vs-int32 edge_index ----
__global__ void init_k(const unsigned* w, unsigned* orw, unsigned* cnt, int E) {
    int t = threadIdx.x;              // 256 threads, 1 block
    for (int i = t; i < NBMAX; i += 256) cnt[i] = 0u;
    __shared__ unsigned s;
    if (t == 0) s = 0u;
    __syncthreads();
    unsigned v = 0;
    int lim = (E < 2048) ? E : 2048;  // stay inside buffer even if int32
    for (int i = t; i < lim; i += 256)
        v |= w[2 * i + 1];            // odd words == 0 iff int64 layout
    atomicOr(&s, v);
    __syncthreads();
    if (t == 0) *orw = s;             // 0 => int64
}

// ---- histogram over destination bins ----
__global__ void hist_k(const void* ei, const unsigned* orw, unsigned* cnt,
                       int E, int NB) {
    __shared__ unsigned lh[NBMAX];
    const bool is64 = (*orw == 0u);
    const int* e32 = (const int*)ei;
    const long long* e64 = (const long long*)ei;
    for (int i = threadIdx.x; i < NB; i += blockDim.x) lh[i] = 0u;
    __syncthreads();
    int t = blockIdx.x * blockDim.x + threadIdx.x;
    int st = gridDim.x * blockDim.x;
    for (int e = t; e < E; e += st) {
        int c = is64 ? (int)e64[E + e] : e32[E + e];
        atomicAdd(&lh[c >> 8], 1u);
    }
    __syncthreads();
    for (int i = threadIdx.x; i < NB; i += blockDim.x) {
        unsigned v = lh[i];
        if (v) atomicAdd(&cnt[i], v);
    }
}

// ---- exclusive scan of cnt[NB] -> offs[NB+1], seed cursors ----
__global__ void scan_k(const unsigned* cnt, unsigned* offs, unsigned* gcur, int NB) {
    __shared__ unsigned sc[NBMAX];
    int t = threadIdx.x;              // 1024 threads, 1 block
    unsigned v0 = (t < NB) ? cnt[t] : 0u;
    sc[t] = v0;
    __syncthreads();
    for (int d = 1; d < 1024; d <<= 1) {
        unsigned v = (t >= d) ? sc[t - d] : 0u;
        __syncthreads();
        sc[t] += v;
        __syncthreads();
    }
    unsigned excl = sc[t] - v0;
    if (t < NB) { offs[t] = excl; gcur[t] = excl; }
    if (t == 0) offs[NB] = sc[NB - 1];
}

// ---- tile-local counting sort -> coalesced payload writes (by bin) ----
__global__ __launch_bounds__(1024)
void scat_k(const void* ei, const float* ea, const unsigned* orw,
            unsigned* gcur, unsigned long long* pay, int E, int NB, int ntiles) {
    __shared__ unsigned long long lp[TILE];   // 48KB
    __shared__ unsigned lh[NBMAX];
    __shared__ unsigned lo[NBMAX + 1];
    __shared__ unsigned gb[NBMAX];
    const bool is64 = (*orw == 0u);
    const int* e32 = (const int*)ei;
    const long long* e64 = (const long long*)ei;
    const int t = threadIdx.x;

    for (int tile = blockIdx.x; tile < ntiles; tile += gridDim.x) {
        int base = tile * TILE;
        int tc = E - base; if (tc > TILE) tc = TILE;

        for (int i = t; i < NB; i += 1024) lh[i] = 0u;
        __syncthreads();

        int bn[EPT]; unsigned rk[EPT]; unsigned long long pv[EPT];
        #pragma unroll
        for (int i = 0; i < EPT; ++i) {
            int e = base + i * 1024 + t;
            bn[i] = -1;
            if (e < base + tc) {
                int c, r;
                if (is64) { c = (int)e64[E + e]; r = (int)e64[e]; }
                else      { c = e32[E + e];      r = e32[e]; }
                float w = ea[e];
                bn[i] = c >> 8;
                pv[i] = ((unsigned long long)__float_as_uint(w) << 32)
                        | ((unsigned)r << 8) | (unsigned)(c & 255);
                rk[i] = atomicAdd(&lh[bn[i]], 1u);
            }
        }
        __syncthreads();

        unsigned v0 = (t < NB) ? lh[t] : 0u;
        lo[t] = v0;
        __syncthreads();
        for (int d = 1; d < 1024; d <<= 1) {
            unsigned v = (t >= d) ? lo[t - d] : 0u;
            __syncthreads();
            lo[t] += v;
            __syncthreads();
        }
        unsigned excl = lo[t] - v0;
        if (t < NB && v0) gb[t] = atomicAdd(&gcur[t], v0);
        if (t < NB) lo[t] = excl;
        if (t == 0) lo[NB] = (unsigned)tc;
        __syncthreads();

        #pragma unroll
        for (int i = 0; i < EPT; ++i)
            if (bn[i] >= 0) lp[lo[bn[i]] + rk[i]] = pv[i];
        __syncthreads();

        for (int s = t; s < tc; s += 1024) {
            int a = 0, b = NB;
            while (b - a > 1) {
                int m = (a + b) >> 1;
                if (lo[m] <= (unsigned)s) a = m; else b = m;
            }
            pay[(size_t)gb[a] + (unsigned)s - lo[a]] = lp[s];
        }
        __syncthreads();
    }
}

// ---- per-bin counting sort by node + deg/rsqrt + per-node offsets ----
__global__ __launch_bounds__(1024)
void sort2_k(const unsigned long long* pay, const unsigned* offs,
             unsigned long long* pay2, unsigned* noffs, float* dis,
             int N, int NB, int E) {
    __shared__ unsigned long long lp[CAP];    // 96KB sorted staging
    __shared__ unsigned cnt[BINSZ];
    __shared__ unsigned loc[BINSZ];
    __shared__ unsigned cur[BINSZ];
    __shared__ float dw[BINSZ];
    int b = blockIdx.x, t = threadIdx.x;
    if (t < BINSZ) { cnt[t] = 0u; dw[t] = 0.f; }
    if (b == 0 && t == 0) noffs[N] = (unsigned)E;
    __syncthreads();
    unsigned base = offs[b], len = offs[b + 1] - base;
    // pass 1: count + weighted degree
    for (unsigned j = t; j < len; j += 1024) {
        unsigned long long p = pay[base + j];
        unsigned lc = (unsigned)p & 255u;
        atomicAdd(&cnt[lc], 1u);
        atomicAdd(&dw[lc], __uint_as_float((unsigned)(p >> 32)));
    }
    __syncthreads();
    // inclusive scan cnt -> loc (256 wide)
    if (t < BINSZ) loc[t] = cnt[t];
    __syncthreads();
    for (int d = 1; d < BINSZ; d <<= 1) {
        unsigned v = 0;
        if (t < BINSZ && t >= d) v = loc[t - d];
        __syncthreads();
        if (t < BINSZ && t >= d) loc[t] += v;
        __syncthreads();
    }
    if (t < BINSZ) {
        unsigned excl = loc[t] - cnt[t];
        cur[t] = excl;
        int node = (b << 8) + t;
        if (node < N) {
            noffs[node] = base + excl;
            float d = 1.0f + dw[t];
            dis[node] = (d > 0.f) ? rsqrtf(d) : 0.f;
        }
    }
    __syncthreads();
    // pass 2: rank + place (LDS for pos<CAP, direct global for rare overflow)
    for (unsigned j = t; j < len; j += 1024) {
        unsigned long long p = pay[base + j];
        unsigned lc = (unsigned)p & 255u;
        unsigned pos = atomicAdd(&cur[lc], 1u);
        if (pos < CAP) lp[pos] = p;
        else pay2[(size_t)base + pos] = p;
    }
    __syncthreads();
    unsigned m = len < CAP ? len : CAP;
    for (unsigned j = t; j < m; j += 1024)
        pay2[(size_t)base + j] = lp[j];
}

// ---- wave-per-node CSR aggregate + fused 8->64 transform + bias ----
// 16 slots x 4 float2 dim-pairs, dual-stream unroll for MLP.
__global__ __launch_bounds__(256)
void agg_k(const unsigned long long* pay2, const unsigned* noffs,
           const float* dis, const float* x, const float* Wm, const float* bv,
           float* out, int N) {
    __shared__ float ag[4][8];
    const float2* x2 = (const float2*)x;
    int t = threadIdx.x;
    int wv = t >> 6, lane = t & 63;
    int slot = lane >> 2, p = lane & 3;
    int node = blockIdx.x * 4 + wv;
    float wr[8];
    #pragma unroll
    for (int k = 0; k < 8; ++k) wr[k] = Wm[k * 64 + lane];
    float o2 = bv[lane];
    float ax = 0.f, ay = 0.f, bx = 0.f, by = 0.f;
    if (node < N) {
        unsigned s = noffs[node], e = noffs[node + 1];
        unsigned j = s + slot;
        for (; j + 16 < e; j += 32) {           // dual independent chains
            unsigned long long pa = pay2[j];
            unsigned long long pb = pay2[j + 16];
            unsigned ra = ((unsigned)pa >> 8) & 0xFFFFFFu;
            unsigned rb = ((unsigned)pb >> 8) & 0xFFFFFFu;
            float aa = dis[ra] * __uint_as_float((unsigned)(pa >> 32));
            float ab = dis[rb] * __uint_as_float((unsigned)(pb >> 32));
            float2 va = x2[(size_t)ra * 4 + p];
            float2 vb = x2[(size_t)rb * 4 + p];
            ax += aa * va.x; ay += aa * va.y;
            bx += ab * vb.x; by += ab * vb.y;
        }
        if (j < e) {                             // at most one remainder
            unsigned long long pa = pay2[j];
            unsigned ra = ((unsigned)pa >> 8) & 0xFFFFFFu;
            float aa = dis[ra] * __uint_as_float((unsigned)(pa >> 32));
            float2 va = x2[(size_t)ra * 4 + p];
            ax += aa * va.x; ay += aa * va.y;
        }
    }
    ax += bx; ay += by;
    #pragma unroll
    for (int m = 4; m <= 32; m <<= 1) {          // reduce over 16 slots
        ax += __shfl_xor(ax, m);
        ay += __shfl_xor(ay, m);
    }
    if (node < N && slot == 0) {                 // lanes 0..3 hold dims {2p,2p+1}
        float dc = dis[node];
        ag[wv][2 * p]     = dc * ax + dc * dc * x[(size_t)node * 8 + 2 * p];
        ag[wv][2 * p + 1] = dc * ay + dc * dc * x[(size_t)node * 8 + 2 * p + 1];
    }
    __syncthreads();
    if (node < N) {
        #pragma unroll
        for (int k = 0; k < 8; ++k) o2 += ag[wv][k] * wr[k];
        out[(size_t)node * 64 + lane] = o2;
    }
}

// ---------------- round-1 fallback (tiny ws) ----------------
__global__ void fb_init_k(float* deg, float4* agg4, int N) {
    int i = blockIdx.x * blockDim.x + threadIdx.x, st = gridDim.x * blockDim.x;
    for (; i < N; i += st) {
        deg[i] = 1.0f;
        agg4[2 * i] = make_float4(0.f, 0.f, 0.f, 0.f);
        agg4[2 * i + 1] = make_float4(0.f, 0.f, 0.f, 0.f);
    }
}
__global__ void fb_deg_k(const void* ei, const float* ea, const unsigned* orw,
                         float* deg, int E) {
    const bool is64 = (*orw == 0u);
    const int* e32 = (const int*)ei;
    const long long* e64 = (const long long*)ei;
    int e = blockIdx.x * blockDim.x + threadIdx.x, st = gridDim.x * blockDim.x;
    for (; e < E; e += st) {
        int c = is64 ? (int)e64[E + e] : e32[E + e];
        atomicAdd(&deg[c], ea[e]);
    }
}
__global__ void fb_dis_k(float* deg, int N) {
    int i = blockIdx.x * blockDim.x + threadIdx.x, st = gridDim.x * blockDim.x;
    for (; i < N; i += st) {
        float d = deg[i];
        deg[i] = (d > 0.f) ? rsqrtf(d) : 0.f;
    }
}
__global__ void fb_edge_k(const void* ei, const float* ea, const unsigned* orw,
                          const float* dis, const float* x, float* agg, int E) {
    const bool is64 = (*orw == 0u);
    const int* e32 = (const int*)ei;
    const long long* e64 = (const long long*)ei;
    int e = blockIdx.x * blockDim.x + threadIdx.x, st = gridDim.x * blockDim.x;
    for (; e < E; e += st) {
        int r, c;
        if (is64) { r = (int)e64[e]; c = (int)e64[E + e]; }
        else      { r = e32[e];      c = e32[E + e]; }
        float nrm = dis[r] * ea[e] * dis[c];
        const float4* xr = (const float4*)(x + (size_t)r * 8);
        float4 a = xr[0], bb = xr[1];
        float* ag = agg + (size_t)c * 8;
        atomicAdd(ag + 0, nrm * a.x);  atomicAdd(ag + 1, nrm * a.y);
        atomicAdd(ag + 2, nrm * a.z);  atomicAdd(ag + 3, nrm * a.w);
        atomicAdd(ag + 4, nrm * bb.x); atomicAdd(ag + 5, nrm * bb.y);
        atomicAdd(ag + 6, nrm * bb.z); atomicAdd(ag + 7, nrm * bb.w);
    }
}
__global__ void fb_out_k(const float* x, const float* Wm, const float* bv,
                         const float* dis, const float* agg, float* out, int N) {
    int lane = threadIdx.x & 63;
    int wid = blockIdx.x * (blockDim.x >> 6) + (threadIdx.x >> 6);
    int nw = gridDim.x * (blockDim.x >> 6);
    float wr[8];
    #pragma unroll
    for (int k = 0; k < 8; ++k) wr[k] = Wm[k * 64 + lane];
    float bj = bv[lane];
    for (int i = wid; i < N; i += nw) {
        float d = dis[i];
        float ink = 0.f;
        if (lane < 8) ink = agg[(size_t)i * 8 + lane] + d * d * x[(size_t)i * 8 + lane];
        float acc = bj;
        #pragma unroll
        for (int k = 0; k < 8; ++k) acc += __shfl(ink, k) * wr[k];
        out[(size_t)i * 64 + lane] = acc;
    }
}

extern "C" void kernel_launch(void* const* d_in, const int* in_sizes, int n_in,
                              void* d_out, int out_size, void* d_ws, size_t ws_size,
                              hipStream_t stream) {
    const float* x  = (const float*)d_in[0];
    const void*  ei = d_in[1];
    const float* ea = (const float*)d_in[2];
    const float* Wm = (const float*)d_in[3];
    const float* bv = (const float*)d_in[4];
    float* out = (float*)d_out;

    const int N = in_sizes[0] / 8;
    const int E = in_sizes[2];
    const int NB = (N + BINSZ - 1) / BINSZ;

    char* ws = (char*)d_ws;
    size_t o = 0;
    unsigned* orw   = (unsigned*)(ws + o); o += 256;
    unsigned* cnt   = (unsigned*)(ws + o); o += ws_align(NBMAX * 4);
    unsigned* offs  = (unsigned*)(ws + o); o += ws_align((NBMAX + 1) * 4);
    unsigned* gcur  = (unsigned*)(ws + o); o += ws_align(NBMAX * 4);
    float* dis      = (float*)(ws + o);    o += ws_align((size_t)N * 4);
    unsigned* noffs = (unsigned*)(ws + o); o += ws_align((size_t)(N + 1) * 4);
    unsigned long long* pay = (unsigned long long*)(ws + o);
    o += ws_align((size_t)E * 8);
    unsigned long long* pay2 = (unsigned long long*)(ws + o);
    o += ws_align((size_t)E * 8);

    const int ntiles = (E + TILE - 1) / TILE;

    if (NB <= NBMAX && E >= 2048 && o <= ws_size) {
        init_k<<<1, 256, 0, stream>>>((const unsigned*)ei, orw, cnt, E);
        hist_k<<<256, 512, 0, stream>>>(ei, orw, cnt, E, NB);
        scan_k<<<1, 1024, 0, stream>>>(cnt, offs, gcur, NB);
        scat_k<<<ntiles, 1024, 0, stream>>>(ei, ea, orw, gcur, pay, E, NB, ntiles);
        sort2_k<<<NB, 1024, 0, stream>>>(pay, offs, pay2, noffs, dis, N, NB, E);
        agg_k<<<(N + 3) / 4, 256, 0, stream>>>(pay2, noffs, dis, x, Wm, bv, out, N);
    } else {
        float* agg = (float*)(ws + 256 + ws_align((size_t)N * 4));
        init_k<<<1, 256, 0, stream>>>((const unsigned*)ei, orw, cnt, E);
        fb_init_k<<<(N + 255) / 256, 256, 0, stream>>>(dis, (float4*)agg, N);
        fb_deg_k<<<2048, 256, 0, stream>>>(ei, ea, orw, dis, E);
        fb_dis_k<<<(N + 255) / 256, 256, 0, stream>>>(dis, N);
        fb_edge_k<<<2048, 256, 0, stream>>>(ei, ea, orw, dis, x, agg, E);
        fb_out_k<<<2048, 256, 0, stream>>>(x, Wm, bv, dis, agg, out, N);
    }
}

// Round 8
// 132.234 us; speedup vs baseline: 12.0168x; 1.0801x over previous
//
#include <hip/hip_runtime.h>

// GCNConv(8->64), self-loops, symmetric norm.
// out[c] = ( dis[c] * sum_e dis[r]*ew*x[r]  +  dis[c]^2 * x[c] ) @ W + b
//
// v8: v7 pipeline with gather-transaction reduction in agg:
//   * y-table: y[r] = dis[r]*x[r] (built in sort2 epilogue) -> agg does
//     ew*y[r], no dis gather; self-loop = dc*y[node].
//   * agg: 32 slots x 2 float4 lanes -> the two 16B half-row reads share one
//     64B line => 1 L1 segment per edge (was 2: x2 + dis).
//   * BINSZ 128, CAP 6144: sort2 LDS ~51KB -> 2 blocks/CU (was 1).
//
// Payload pack (u64): ew_bits(32) | row(24) | lcol(8). Valid for N <= 2^24.

#define NBMAX 1024          // max bins => N <= 131072 (fallback beyond)
#define PSH   7
#define BINSZ 128
#define TILE  6144          // edges per scatter tile (LDS: 48KB payload)
#define EPT   6             // TILE / 1024 threads
#define CAP   6144          // max edges per bin staged in LDS by sort2

static inline size_t ws_align(size_t x) { return (x + 255) & ~(size_t)255; }

// ---- init: zero bin counters + detect int64-vs-int32 edge_index ----
__global__ void init_k(const unsigned* w, unsigned* orw, unsigned* cnt, int E) {
    int t = threadIdx.x;              // 256 threads, 1 block
    for (int i = t; i < NBMAX; i += 256) cnt[i] = 0u;
    __shared__ unsigned s;
    if (t == 0) s = 0u;
    __syncthreads();
    unsigned v = 0;
    int lim = (E < 2048) ? E : 2048;  // stay inside buffer even if int32
    for (int i = t; i < lim; i += 256)
        v |= w[2 * i + 1];            // odd words == 0 iff int64 layout
    atomicOr(&s, v);
    __syncthreads();
    if (t == 0) *orw = s;             // 0 => int64
}

// ---- histogram over destination bins ----
__global__ void hist_k(const void* ei, const unsigned* orw, unsigned* cnt,
                       int E, int NB) {
    __shared__ unsigned lh[NBMAX];
    const bool is64 = (*orw == 0u);
    const int* e32 = (const int*)ei;
    const long long* e64 = (const long long*)ei;
    for (int i = threadIdx.x; i < NB; i += blockDim.x) lh[i] = 0u;
    __syncthreads();
    int t = blockIdx.x * blockDim.x + threadIdx.x;
    int st = gridDim.x * blockDim.x;
    for (int e = t; e < E; e += st) {
        int c = is64 ? (int)e64[E + e] : e32[E + e];
        atomicAdd(&lh[c >> PSH], 1u);
    }
    __syncthreads();
    for (int i = threadIdx.x; i < NB; i += blockDim.x) {
        unsigned v = lh[i];
        if (v) atomicAdd(&cnt[i], v);
    }
}

// ---- exclusive scan of cnt[NB] -> offs[NB+1], seed cursors ----
__global__ void scan_k(const unsigned* cnt, unsigned* offs, unsigned* gcur, int NB) {
    __shared__ unsigned sc[NBMAX];
    int t = threadIdx.x;              // 1024 threads, 1 block
    unsigned v0 = (t < NB) ? cnt[t] : 0u;
    sc[t] = v0;
    __syncthreads();
    for (int d = 1; d < 1024; d <<= 1) {
        unsigned v = (t >= d) ? sc[t - d] : 0u;
        __syncthreads();
        sc[t] += v;
        __syncthreads();
    }
    unsigned excl = sc[t] - v0;
    if (t < NB) { offs[t] = excl; gcur[t] = excl; }
    if (t == 0) offs[NB] = sc[NB - 1];
}

// ---- tile-local counting sort -> coalesced payload writes (by bin) ----
__global__ __launch_bounds__(1024)
void scat_k(const void* ei, const float* ea, const unsigned* orw,
            unsigned* gcur, unsigned long long* pay, int E, int NB, int ntiles) {
    __shared__ unsigned long long lp[TILE];   // 48KB
    __shared__ unsigned lh[NBMAX];
    __shared__ unsigned lo[NBMAX + 1];
    __shared__ unsigned gb[NBMAX];
    const bool is64 = (*orw == 0u);
    const int* e32 = (const int*)ei;
    const long long* e64 = (const long long*)ei;
    const int t = threadIdx.x;

    for (int tile = blockIdx.x; tile < ntiles; tile += gridDim.x) {
        int base = tile * TILE;
        int tc = E - base; if (tc > TILE) tc = TILE;

        for (int i = t; i < NB; i += 1024) lh[i] = 0u;
        __syncthreads();

        int bn[EPT]; unsigned rk[EPT]; unsigned long long pv[EPT];
        #pragma unroll
        for (int i = 0; i < EPT; ++i) {
            int e = base + i * 1024 + t;
            bn[i] = -1;
            if (e < base + tc) {
                int c, r;
                if (is64) { c = (int)e64[E + e]; r = (int)e64[e]; }
                else      { c = e32[E + e];      r = e32[e]; }
                float w = ea[e];
                bn[i] = c >> PSH;
                pv[i] = ((unsigned long long)__float_as_uint(w) << 32)
                        | ((unsigned)r << 8) | (unsigned)(c & (BINSZ - 1));
                rk[i] = atomicAdd(&lh[bn[i]], 1u);
            }
        }
        __syncthreads();

        unsigned v0 = (t < NB) ? lh[t] : 0u;
        lo[t] = v0;
        __syncthreads();
        for (int d = 1; d < 1024; d <<= 1) {
            unsigned v = (t >= d) ? lo[t - d] : 0u;
            __syncthreads();
            lo[t] += v;
            __syncthreads();
        }
        unsigned excl = lo[t] - v0;
        if (t < NB && v0) gb[t] = atomicAdd(&gcur[t], v0);
        if (t < NB) lo[t] = excl;
        if (t == 0) lo[NB] = (unsigned)tc;
        __syncthreads();

        #pragma unroll
        for (int i = 0; i < EPT; ++i)
            if (bn[i] >= 0) lp[lo[bn[i]] + rk[i]] = pv[i];
        __syncthreads();

        for (int s = t; s < tc; s += 1024) {
            int a = 0, b = NB;
            while (b - a > 1) {
                int m = (a + b) >> 1;
                if (lo[m] <= (unsigned)s) a = m; else b = m;
            }
            pay[(size_t)gb[a] + (unsigned)s - lo[a]] = lp[s];
        }
        __syncthreads();
    }
}

// ---- per-bin counting sort by node + deg/rsqrt/noffs + y-table ----
__global__ __launch_bounds__(1024)
void sort2_k(const unsigned long long* pay, const unsigned* offs,
             unsigned long long* pay2, unsigned* noffs, float* dis,
             const float* x, float* y, int N, int E) {
    __shared__ unsigned long long lp[CAP];    // 48KB sorted staging
    __shared__ unsigned cnt[BINSZ];
    __shared__ unsigned loc[BINSZ];
    __shared__ unsigned cur[BINSZ];
    __shared__ float dw[BINSZ];
    __shared__ float sdis[BINSZ];
    int b = blockIdx.x, t = threadIdx.x;
    if (t < BINSZ) { cnt[t] = 0u; dw[t] = 0.f; }
    if (b == 0 && t == 0) noffs[N] = (unsigned)E;
    __syncthreads();
    unsigned base = offs[b], len = offs[b + 1] - base;
    // pass 1: count + weighted degree
    for (unsigned j = t; j < len; j += 1024) {
        unsigned long long p = pay[base + j];
        unsigned lc = (unsigned)p & 255u;
        atomicAdd(&cnt[lc], 1u);
        atomicAdd(&dw[lc], __uint_as_float((unsigned)(p >> 32)));
    }
    __syncthreads();
    // inclusive scan cnt -> loc
    if (t < BINSZ) loc[t] = cnt[t];
    __syncthreads();
    for (int d = 1; d < BINSZ; d <<= 1) {
        unsigned v = 0;
        if (t < BINSZ && t >= d) v = loc[t - d];
        __syncthreads();
        if (t < BINSZ && t >= d) loc[t] += v;
        __syncthreads();
    }
    if (t < BINSZ) {
        unsigned excl = loc[t] - cnt[t];
        cur[t] = excl;
        int node = b * BINSZ + t;
        float dval = 0.f;
        if (node < N) {
            noffs[node] = base + excl;
            float d = 1.0f + dw[t];
            dval = (d > 0.f) ? rsqrtf(d) : 0.f;
            dis[node] = dval;
        }
        sdis[t] = dval;
    }
    __syncthreads();
    // pass 2: rank + place (LDS; global direct for pathological overflow)
    for (unsigned j = t; j < len; j += 1024) {
        unsigned long long p = pay[base + j];
        unsigned lc = (unsigned)p & 255u;
        unsigned pos = atomicAdd(&cur[lc], 1u);
        if (pos < CAP) lp[pos] = p;
        else pay2[(size_t)base + pos] = p;
    }
    __syncthreads();
    unsigned m = len < CAP ? len : CAP;
    for (unsigned j = t; j < m; j += 1024)
        pay2[(size_t)base + j] = lp[j];
    // y-table epilogue: y[node] = dis[node] * x[node], coalesced
    int gbase = b * (BINSZ * 8);
    int gi = gbase + t;                       // BINSZ*8 == 1024 == blockDim
    if (t < BINSZ * 8 && gi < N * 8)
        y[gi] = sdis[t >> 3] * x[gi];
}

// ---- wave-per-node CSR aggregate + fused 8->64 transform + bias ----
// 32 slots x 2 float4 lanes: both 16B half-row reads hit one 64B line
// => 1 L1 segment per edge.
__global__ __launch_bounds__(256)
void agg_k(const unsigned long long* pay2, const unsigned* noffs,
           const float* dis, const float* y, const float* Wm, const float* bv,
           float* out, int N) {
    __shared__ float ag[4][8];
    const float4* y4 = (const float4*)y;
    int t = threadIdx.x;
    int wv = t >> 6, lane = t & 63;
    int slot = lane >> 1, h = lane & 1;
    int node = blockIdx.x * 4 + wv;
    float wr[8];
    #pragma unroll
    for (int k = 0; k < 8; ++k) wr[k] = Wm[k * 64 + lane];
    float o2 = bv[lane];
    float a0 = 0.f, a1 = 0.f, a2 = 0.f, a3 = 0.f;
    if (node < N) {
        unsigned s = noffs[node], e = noffs[node + 1];
        for (unsigned j = s + slot; j < e; j += 32) {
            unsigned long long p = pay2[j];
            unsigned r = ((unsigned)p >> 8) & 0xFFFFFFu;
            float ew = __uint_as_float((unsigned)(p >> 32));
            float4 v = y4[(size_t)r * 2 + h];
            a0 += ew * v.x; a1 += ew * v.y; a2 += ew * v.z; a3 += ew * v.w;
        }
    }
    #pragma unroll
    for (int m = 2; m <= 32; m <<= 1) {       // reduce over 32 slots
        a0 += __shfl_xor(a0, m);
        a1 += __shfl_xor(a1, m);
        a2 += __shfl_xor(a2, m);
        a3 += __shfl_xor(a3, m);
    }
    if (node < N && slot == 0) {              // lanes 0 (h=0), 1 (h=1)
        float dc = dis[node];
        float4 vy = y4[(size_t)node * 2 + h]; // dc*x[node] -> self-loop = dc*vy
        ag[wv][h * 4 + 0] = dc * (a0 + vy.x);
        ag[wv][h * 4 + 1] = dc * (a1 + vy.y);
        ag[wv][h * 4 + 2] = dc * (a2 + vy.z);
        ag[wv][h * 4 + 3] = dc * (a3 + vy.w);
    }
    __syncthreads();
    if (node < N) {
        #pragma unroll
        for (int k = 0; k < 8; ++k) o2 += ag[wv][k] * wr[k];
        out[(size_t)node * 64 + lane] = o2;
    }
}

// ---------------- round-1 fallback (tiny ws / huge N) ----------------
__global__ void fb_init_k(float* deg, float4* agg4, int N) {
    int i = blockIdx.x * blockDim.x + threadIdx.x, st = gridDim.x * blockDim.x;
    for (; i < N; i += st) {
        deg[i] = 1.0f;
        agg4[2 * i] = make_float4(0.f, 0.f, 0.f, 0.f);
        agg4[2 * i + 1] = make_float4(0.f, 0.f, 0.f, 0.f);
    }
}
__global__ void fb_deg_k(const void* ei, const float* ea, const unsigned* orw,
                         float* deg, int E) {
    const bool is64 = (*orw == 0u);
    const int* e32 = (const int*)ei;
    const long long* e64 = (const long long*)ei;
    int e = blockIdx.x * blockDim.x + threadIdx.x, st = gridDim.x * blockDim.x;
    for (; e < E; e += st) {
        int c = is64 ? (int)e64[E + e] : e32[E + e];
        atomicAdd(&deg[c], ea[e]);
    }
}
__global__ void fb_dis_k(float* deg, int N) {
    int i = blockIdx.x * blockDim.x + threadIdx.x, st = gridDim.x * blockDim.x;
    for (; i < N; i += st) {
        float d = deg[i];
        deg[i] = (d > 0.f) ? rsqrtf(d) : 0.f;
    }
}
__global__ void fb_edge_k(const void* ei, const float* ea, const unsigned* orw,
                          const float* dis, const float* x, float* agg, int E) {
    const bool is64 = (*orw == 0u);
    const int* e32 = (const int*)ei;
    const long long* e64 = (const long long*)ei;
    int e = blockIdx.x * blockDim.x + threadIdx.x, st = gridDim.x * blockDim.x;
    for (; e < E; e += st) {
        int r, c;
        if (is64) { r = (int)e64[e]; c = (int)e64[E + e]; }
        else      { r = e32[e];      c = e32[E + e]; }
        float nrm = dis[r] * ea[e] * dis[c];
        const float4* xr = (const float4*)(x + (size_t)r * 8);
        float4 a = xr[0], bb = xr[1];
        float* ag = agg + (size_t)c * 8;
        atomicAdd(ag + 0, nrm * a.x);  atomicAdd(ag + 1, nrm * a.y);
        atomicAdd(ag + 2, nrm * a.z);  atomicAdd(ag + 3, nrm * a.w);
        atomicAdd(ag + 4, nrm * bb.x); atomicAdd(ag + 5, nrm * bb.y);
        atomicAdd(ag + 6, nrm * bb.z); atomicAdd(ag + 7, nrm * bb.w);
    }
}
__global__ void fb_out_k(const float* x, const float* Wm, const float* bv,
                         const float* dis, const float* agg, float* out, int N) {
    int lane = threadIdx.x & 63;
    int wid = blockIdx.x * (blockDim.x >> 6) + (threadIdx.x >> 6);
    int nw = gridDim.x * (blockDim.x >> 6);
    float wr[8];
    #pragma unroll
    for (int k = 0; k < 8; ++k) wr[k] = Wm[k * 64 + lane];
    float bj = bv[lane];
    for (int i = wid; i < N; i += nw) {
        float d = dis[i];
        float ink = 0.f;
        if (lane < 8) ink = agg[(size_t)i * 8 + lane] + d * d * x[(size_t)i * 8 + lane];
        float acc = bj;
        #pragma unroll
        for (int k = 0; k < 8; ++k) acc += __shfl(ink, k) * wr[k];
        out[(size_t)i * 64 + lane] = acc;
    }
}

extern "C" void kernel_launch(void* const* d_in, const int* in_sizes, int n_in,
                              void* d_out, int out_size, void* d_ws, size_t ws_size,
                              hipStream_t stream) {
    const float* x  = (const float*)d_in[0];
    const void*  ei = d_in[1];
    const float* ea = (const float*)d_in[2];
    const float* Wm = (const float*)d_in[3];
    const float* bv = (const float*)d_in[4];
    float* out = (float*)d_out;

    const int N = in_sizes[0] / 8;
    const int E = in_sizes[2];
    const int NB = (N + BINSZ - 1) / BINSZ;

    char* ws = (char*)d_ws;
    size_t o = 0;
    unsigned* orw   = (unsigned*)(ws + o); o += 256;
    unsigned* cnt   = (unsigned*)(ws + o); o += ws_align(NBMAX * 4);
    unsigned* offs  = (unsigned*)(ws + o); o += ws_align((NBMAX + 1) * 4);
    unsigned* gcur  = (unsigned*)(ws + o); o += ws_align(NBMAX * 4);
    float* dis      = (float*)(ws + o);    o += ws_align((size_t)N * 4);
    unsigned* noffs = (unsigned*)(ws + o); o += ws_align((size_t)(N + 1) * 4);
    float* y        = (float*)(ws + o);    o += ws_align((size_t)N * 8 * 4);
    unsigned long long* pay = (unsigned long long*)(ws + o);
    o += ws_align((size_t)E * 8);
    unsigned long long* pay2 = (unsigned long long*)(ws + o);
    o += ws_align((size_t)E * 8);

    const int ntiles = (E + TILE - 1) / TILE;

    if (NB <= NBMAX && E >= 2048 && o <= ws_size) {
        init_k<<<1, 256, 0, stream>>>((const unsigned*)ei, orw, cnt, E);
        hist_k<<<256, 512, 0, stream>>>(ei, orw, cnt, E, NB);
        scan_k<<<1, 1024, 0, stream>>>(cnt, offs, gcur, NB);
        scat_k<<<ntiles, 1024, 0, stream>>>(ei, ea, orw, gcur, pay, E, NB, ntiles);
        sort2_k<<<NB, 1024, 0, stream>>>(pay, offs, pay2, noffs, dis, x, y, N, E);
        agg_k<<<(N + 3) / 4, 256, 0, stream>>>(pay2, noffs, dis, y, Wm, bv, out, N);
    } else {
        float* agg = (float*)(ws + 256 + ws_align((size_t)N * 4));
        init_k<<<1, 256, 0, stream>>>((const unsigned*)ei, orw, cnt, E);
        fb_init_k<<<(N + 255) / 256, 256, 0, stream>>>(dis, (float4*)agg, N);
        fb_deg_k<<<2048, 256, 0, stream>>>(ei, ea, orw, dis, E);
        fb_dis_k<<<(N + 255) / 256, 256, 0, stream>>>(dis, N);
        fb_edge_k<<<2048, 256, 0, stream>>>(ei, ea, orw, dis, x, agg, E);
        fb_out_k<<<2048, 256, 0, stream>>>(x, Wm, bv, dis, agg, out, N);
    }
}

// Round 9
// 129.129 us; speedup vs baseline: 12.3057x; 1.0240x over previous
//
#include <hip/hip_runtime.h>

// GCNConv(8->64), self-loops, symmetric norm.
// out[c] = ( dis[c] * sum_e dis[r]*ew*x[r]  +  dis[c]^2 * x[c] ) @ W + b
//
// v9 = v8 with scat flush de-searched:
//   * lbin[pos] records each placed element's bin (1 LDS write/edge), so the
//     coalesced flush does 3 LDS reads instead of a ~10-read binary search
//     (r8: ~256M divergent LDS reads were most of scat's ~45us).
//   * TILE 4096 (EPT 4): scat LDS ~53KB -> 3 blocks/CU.
// agg_k is at the TA floor (25.6M distinct-line gathers ~= 42us): unchanged.
//
// Payload pack (u64): ew_bits(32) | row(24) | lcol(8). Valid for N <= 2^24.

#define NBMAX 1024          // max bins => N <= 131072 (fallback beyond)
#define PSH   7
#define BINSZ 128
#define TILE  4096          // edges per scatter tile (LDS: 32KB payload)
#define EPT   4             // TILE / 1024 threads
#define CAP   6144          // max edges per bin staged in LDS by sort2

static inline size_t ws_align(size_t x) { return (x + 255) & ~(size_t)255; }

// ---- init: zero bin counters + detect int64-vs-int32 edge_index ----
__global__ void init_k(const unsigned* w, unsigned* orw, unsigned* cnt, int E) {
    int t = threadIdx.x;              // 256 threads, 1 block
    for (int i = t; i < NBMAX; i += 256) cnt[i] = 0u;
    __shared__ unsigned s;
    if (t == 0) s = 0u;
    __syncthreads();
    unsigned v = 0;
    int lim = (E < 2048) ? E : 2048;  // stay inside buffer even if int32
    for (int i = t; i < lim; i += 256)
        v |= w[2 * i + 1];            // odd words == 0 iff int64 layout
    atomicOr(&s, v);
    __syncthreads();
    if (t == 0) *orw = s;             // 0 => int64
}

// ---- histogram over destination bins ----
__global__ void hist_k(const void* ei, const unsigned* orw, unsigned* cnt,
                       int E, int NB) {
    __shared__ unsigned lh[NBMAX];
    const bool is64 = (*orw == 0u);
    const int* e32 = (const int*)ei;
    const long long* e64 = (const long long*)ei;
    for (int i = threadIdx.x; i < NB; i += blockDim.x) lh[i] = 0u;
    __syncthreads();
    int t = blockIdx.x * blockDim.x + threadIdx.x;
    int st = gridDim.x * blockDim.x;
    for (int e = t; e < E; e += st) {
        int c = is64 ? (int)e64[E + e] : e32[E + e];
        atomicAdd(&lh[c >> PSH], 1u);
    }
    __syncthreads();
    for (int i = threadIdx.x; i < NB; i += blockDim.x) {
        unsigned v = lh[i];
        if (v) atomicAdd(&cnt[i], v);
    }
}

// ---- exclusive scan of cnt[NB] -> offs[NB+1], seed cursors ----
__global__ void scan_k(const unsigned* cnt, unsigned* offs, unsigned* gcur, int NB) {
    __shared__ unsigned sc[NBMAX];
    int t = threadIdx.x;              // 1024 threads, 1 block
    unsigned v0 = (t < NB) ? cnt[t] : 0u;
    sc[t] = v0;
    __syncthreads();
    for (int d = 1; d < 1024; d <<= 1) {
        unsigned v = (t >= d) ? sc[t - d] : 0u;
        __syncthreads();
        sc[t] += v;
        __syncthreads();
    }
    unsigned excl = sc[t] - v0;
    if (t < NB) { offs[t] = excl; gcur[t] = excl; }
    if (t == 0) offs[NB] = sc[NB - 1];
}

// ---- tile-local counting sort -> coalesced payload writes (by bin) ----
__global__ __launch_bounds__(1024)
void scat_k(const void* ei, const float* ea, const unsigned* orw,
            unsigned* gcur, unsigned long long* pay, int E, int NB, int ntiles) {
    __shared__ unsigned long long lp[TILE];   // 32KB
    __shared__ unsigned short lbin[TILE];     // 8KB: bin of sorted element
    __shared__ unsigned lh[NBMAX];
    __shared__ unsigned lo[NBMAX + 1];
    __shared__ unsigned gb[NBMAX];
    const bool is64 = (*orw == 0u);
    const int* e32 = (const int*)ei;
    const long long* e64 = (const long long*)ei;
    const int t = threadIdx.x;

    for (int tile = blockIdx.x; tile < ntiles; tile += gridDim.x) {
        int base = tile * TILE;
        int tc = E - base; if (tc > TILE) tc = TILE;

        for (int i = t; i < NB; i += 1024) lh[i] = 0u;
        __syncthreads();

        int bn[EPT]; unsigned rk[EPT]; unsigned long long pv[EPT];
        #pragma unroll
        for (int i = 0; i < EPT; ++i) {
            int e = base + i * 1024 + t;
            bn[i] = -1;
            if (e < base + tc) {
                int c, r;
                if (is64) { c = (int)e64[E + e]; r = (int)e64[e]; }
                else      { c = e32[E + e];      r = e32[e]; }
                float w = ea[e];
                bn[i] = c >> PSH;
                pv[i] = ((unsigned long long)__float_as_uint(w) << 32)
                        | ((unsigned)r << 8) | (unsigned)(c & (BINSZ - 1));
                rk[i] = atomicAdd(&lh[bn[i]], 1u);
            }
        }
        __syncthreads();

        unsigned v0 = (t < NB) ? lh[t] : 0u;
        lo[t] = v0;
        __syncthreads();
        for (int d = 1; d < 1024; d <<= 1) {
            unsigned v = (t >= d) ? lo[t - d] : 0u;
            __syncthreads();
            lo[t] += v;
            __syncthreads();
        }
        unsigned excl = lo[t] - v0;
        if (t < NB && v0) gb[t] = atomicAdd(&gcur[t], v0);
        if (t < NB) lo[t] = excl;
        if (t == 0) lo[NB] = (unsigned)tc;
        __syncthreads();

        // place payloads into LDS sorted by bin, recording each slot's bin
        #pragma unroll
        for (int i = 0; i < EPT; ++i)
            if (bn[i] >= 0) {
                unsigned pos = lo[bn[i]] + rk[i];
                lp[pos] = pv[i];
                lbin[pos] = (unsigned short)bn[i];
            }
        __syncthreads();

        // flush: direct bin lookup (no binary search)
        for (int s = t; s < tc; s += 1024) {
            int a = lbin[s];
            pay[(size_t)gb[a] + (unsigned)s - lo[a]] = lp[s];
        }
        __syncthreads();
    }
}

// ---- per-bin counting sort by node + deg/rsqrt/noffs + y-table ----
__global__ __launch_bounds__(1024)
void sort2_k(const unsigned long long* pay, const unsigned* offs,
             unsigned long long* pay2, unsigned* noffs, float* dis,
             const float* x, float* y, int N, int E) {
    __shared__ unsigned long long lp[CAP];    // 48KB sorted staging
    __shared__ unsigned cnt[BINSZ];
    __shared__ unsigned loc[BINSZ];
    __shared__ unsigned cur[BINSZ];
    __shared__ float dw[BINSZ];
    __shared__ float sdis[BINSZ];
    int b = blockIdx.x, t = threadIdx.x;
    if (t < BINSZ) { cnt[t] = 0u; dw[t] = 0.f; }
    if (b == 0 && t == 0) noffs[N] = (unsigned)E;
    __syncthreads();
    unsigned base = offs[b], len = offs[b + 1] - base;
    // pass 1: count + weighted degree
    for (unsigned j = t; j < len; j += 1024) {
        unsigned long long p = pay[base + j];
        unsigned lc = (unsigned)p & 255u;
        atomicAdd(&cnt[lc], 1u);
        atomicAdd(&dw[lc], __uint_as_float((unsigned)(p >> 32)));
    }
    __syncthreads();
    // inclusive scan cnt -> loc
    if (t < BINSZ) loc[t] = cnt[t];
    __syncthreads();
    for (int d = 1; d < BINSZ; d <<= 1) {
        unsigned v = 0;
        if (t < BINSZ && t >= d) v = loc[t - d];
        __syncthreads();
        if (t < BINSZ && t >= d) loc[t] += v;
        __syncthreads();
    }
    if (t < BINSZ) {
        unsigned excl = loc[t] - cnt[t];
        cur[t] = excl;
        int node = b * BINSZ + t;
        float dval = 0.f;
        if (node < N) {
            noffs[node] = base + excl;
            float d = 1.0f + dw[t];
            dval = (d > 0.f) ? rsqrtf(d) : 0.f;
            dis[node] = dval;
        }
        sdis[t] = dval;
    }
    __syncthreads();
    // pass 2: rank + place (LDS; global direct for pathological overflow)
    for (unsigned j = t; j < len; j += 1024) {
        unsigned long long p = pay[base + j];
        unsigned lc = (unsigned)p & 255u;
        unsigned pos = atomicAdd(&cur[lc], 1u);
        if (pos < CAP) lp[pos] = p;
        else pay2[(size_t)base + pos] = p;
    }
    __syncthreads();
    unsigned m = len < CAP ? len : CAP;
    for (unsigned j = t; j < m; j += 1024)
        pay2[(size_t)base + j] = lp[j];
    // y-table epilogue: y[node] = dis[node] * x[node], coalesced
    int gbase = b * (BINSZ * 8);
    int gi = gbase + t;                       // BINSZ*8 == 1024 == blockDim
    if (t < BINSZ * 8 && gi < N * 8)
        y[gi] = sdis[t >> 3] * x[gi];
}

// ---- wave-per-node CSR aggregate + fused 8->64 transform + bias ----
// 32 slots x 2 float4 lanes: both 16B half-row reads hit one 64B line
// => 1 L1 segment per edge (TA floor ~42us on this chip).
__global__ __launch_bounds__(256)
void agg_k(const unsigned long long* pay2, const unsigned* noffs,
           const float* dis, const float* y, const float* Wm, const float* bv,
           float* out, int N) {
    __shared__ float ag[4][8];
    const float4* y4 = (const float4*)y;
    int t = threadIdx.x;
    int wv = t >> 6, lane = t & 63;
    int slot = lane >> 1, h = lane & 1;
    int node = blockIdx.x * 4 + wv;
    float wr[8];
    #pragma unroll
    for (int k = 0; k < 8; ++k) wr[k] = Wm[k * 64 + lane];
    float o2 = bv[lane];
    float a0 = 0.f, a1 = 0.f, a2 = 0.f, a3 = 0.f;
    if (node < N) {
        unsigned s = noffs[node], e = noffs[node + 1];
        for (unsigned j = s + slot; j < e; j += 32) {
            unsigned long long p = pay2[j];
            unsigned r = ((unsigned)p >> 8) & 0xFFFFFFu;
            float ew = __uint_as_float((unsigned)(p >> 32));
            float4 v = y4[(size_t)r * 2 + h];
            a0 += ew * v.x; a1 += ew * v.y; a2 += ew * v.z; a3 += ew * v.w;
        }
    }
    #pragma unroll
    for (int m = 2; m <= 32; m <<= 1) {       // reduce over 32 slots
        a0 += __shfl_xor(a0, m);
        a1 += __shfl_xor(a1, m);
        a2 += __shfl_xor(a2, m);
        a3 += __shfl_xor(a3, m);
    }
    if (node < N && slot == 0) {              // lanes 0 (h=0), 1 (h=1)
        float dc = dis[node];
        float4 vy = y4[(size_t)node * 2 + h]; // dc*x[node] -> self-loop = dc*vy
        ag[wv][h * 4 + 0] = dc * (a0 + vy.x);
        ag[wv][h * 4 + 1] = dc * (a1 + vy.y);
        ag[wv][h * 4 + 2] = dc * (a2 + vy.z);
        ag[wv][h * 4 + 3] = dc * (a3 + vy.w);
    }
    __syncthreads();
    if (node < N) {
        #pragma unroll
        for (int k = 0; k < 8; ++k) o2 += ag[wv][k] * wr[k];
        out[(size_t)node * 64 + lane] = o2;
    }
}

// ---------------- round-1 fallback (tiny ws / huge N) ----------------
__global__ void fb_init_k(float* deg, float4* agg4, int N) {
    int i = blockIdx.x * blockDim.x + threadIdx.x, st = gridDim.x * blockDim.x;
    for (; i < N; i += st) {
        deg[i] = 1.0f;
        agg4[2 * i] = make_float4(0.f, 0.f, 0.f, 0.f);
        agg4[2 * i + 1] = make_float4(0.f, 0.f, 0.f, 0.f);
    }
}
__global__ void fb_deg_k(const void* ei, const float* ea, const unsigned* orw,
                         float* deg, int E) {
    const bool is64 = (*orw == 0u);
    const int* e32 = (const int*)ei;
    const long long* e64 = (const long long*)ei;
    int e = blockIdx.x * blockDim.x + threadIdx.x, st = gridDim.x * blockDim.x;
    for (; e < E; e += st) {
        int c = is64 ? (int)e64[E + e] : e32[E + e];
        atomicAdd(&deg[c], ea[e]);
    }
}
__global__ void fb_dis_k(float* deg, int N) {
    int i = blockIdx.x * blockDim.x + threadIdx.x, st = gridDim.x * blockDim.x;
    for (; i < N; i += st) {
        float d = deg[i];
        deg[i] = (d > 0.f) ? rsqrtf(d) : 0.f;
    }
}
__global__ void fb_edge_k(const void* ei, const float* ea, const unsigned* orw,
                          const float* dis, const float* x, float* agg, int E) {
    const bool is64 = (*orw == 0u);
    const int* e32 = (const int*)ei;
    const long long* e64 = (const long long*)ei;
    int e = blockIdx.x * blockDim.x + threadIdx.x, st = gridDim.x * blockDim.x;
    for (; e < E; e += st) {
        int r, c;
        if (is64) { r = (int)e64[e]; c = (int)e64[E + e]; }
        else      { r = e32[e];      c = e32[E + e]; }
        float nrm = dis[r] * ea[e] * dis[c];
        const float4* xr = (const float4*)(x + (size_t)r * 8);
        float4 a = xr[0], bb = xr[1];
        float* ag = agg + (size_t)c * 8;
        atomicAdd(ag + 0, nrm * a.x);  atomicAdd(ag + 1, nrm * a.y);
        atomicAdd(ag + 2, nrm * a.z);  atomicAdd(ag + 3, nrm * a.w);
        atomicAdd(ag + 4, nrm * bb.x); atomicAdd(ag + 5, nrm * bb.y);
        atomicAdd(ag + 6, nrm * bb.z); atomicAdd(ag + 7, nrm * bb.w);
    }
}
__global__ void fb_out_k(const float* x, const float* Wm, const float* bv,
                         const float* dis, const float* agg, float* out, int N) {
    int lane = threadIdx.x & 63;
    int wid = blockIdx.x * (blockDim.x >> 6) + (threadIdx.x >> 6);
    int nw = gridDim.x * (blockDim.x >> 6);
    float wr[8];
    #pragma unroll
    for (int k = 0; k < 8; ++k) wr[k] = Wm[k * 64 + lane];
    float bj = bv[lane];
    for (int i = wid; i < N; i += nw) {
        float d = dis[i];
        float ink = 0.f;
        if (lane < 8) ink = agg[(size_t)i * 8 + lane] + d * d * x[(size_t)i * 8 + lane];
        float acc = bj;
        #pragma unroll
        for (int k = 0; k < 8; ++k) acc += __shfl(ink, k) * wr[k];
        out[(size_t)i * 64 + lane] = acc;
    }
}

extern "C" void kernel_launch(void* const* d_in, const int* in_sizes, int n_in,
                              void* d_out, int out_size, void* d_ws, size_t ws_size,
                              hipStream_t stream) {
    const float* x  = (const float*)d_in[0];
    const void*  ei = d_in[1];
    const float* ea = (const float*)d_in[2];
    const float* Wm = (const float*)d_in[3];
    const float* bv = (const float*)d_in[4];
    float* out = (float*)d_out;

    const int N = in_sizes[0] / 8;
    const int E = in_sizes[2];
    const int NB = (N + BINSZ - 1) / BINSZ;

    char* ws = (char*)d_ws;
    size_t o = 0;
    unsigned* orw   = (unsigned*)(ws + o); o += 256;
    unsigned* cnt   = (unsigned*)(ws + o); o += ws_align(NBMAX * 4);
    unsigned* offs  = (unsigned*)(ws + o); o += ws_align((NBMAX + 1) * 4);
    unsigned* gcur  = (unsigned*)(ws + o); o += ws_align(NBMAX * 4);
    float* dis      = (float*)(ws + o);    o += ws_align((size_t)N * 4);
    unsigned* noffs = (unsigned*)(ws + o); o += ws_align((size_t)(N + 1) * 4);
    float* y        = (float*)(ws + o);    o += ws_align((size_t)N * 8 * 4);
    unsigned long long* pay = (unsigned long long*)(ws + o);
    o += ws_align((size_t)E * 8);
    unsigned long long* pay2 = (unsigned long long*)(ws + o);
    o += ws_align((size_t)E * 8);

    const int ntiles = (E + TILE - 1) / TILE;

    if (NB <= NBMAX && E >= 2048 && o <= ws_size) {
        init_k<<<1, 256, 0, stream>>>((const unsigned*)ei, orw, cnt, E);
        hist_k<<<256, 512, 0, stream>>>(ei, orw, cnt, E, NB);
        scan_k<<<1, 1024, 0, stream>>>(cnt, offs, gcur, NB);
        scat_k<<<ntiles, 1024, 0, stream>>>(ei, ea, orw, gcur, pay, E, NB, ntiles);
        sort2_k<<<NB, 1024, 0, stream>>>(pay, offs, pay2, noffs, dis, x, y, N, E);
        agg_k<<<(N + 3) / 4, 256, 0, stream>>>(pay2, noffs, dis, y, Wm, bv, out, N);
    } else {
        float* agg = (float*)(ws + 256 + ws_align((size_t)N * 4));
        init_k<<<1, 256, 0, stream>>>((const unsigned*)ei, orw, cnt, E);
        fb_init_k<<<(N + 255) / 256, 256, 0, stream>>>(dis, (float4*)agg, N);
        fb_deg_k<<<2048, 256, 0, stream>>>(ei, ea, orw, dis, E);
        fb_dis_k<<<(N + 255) / 256, 256, 0, stream>>>(dis, N);
        fb_edge_k<<<2048, 256, 0, stream>>>(ei, ea, orw, dis, x, agg, E);
        fb_out_k<<<2048, 256, 0, stream>>>(x, Wm, bv, dis, agg, out, N);
    }
}

// Round 10
// 128.340 us; speedup vs baseline: 12.3814x; 1.0062x over previous
//
#include <hip/hip_runtime.h>

// GCNConv(8->64), self-loops, symmetric norm.
// out[c] = ( dis[c] * sum_e dis[r]*ew*x[r]  +  dis[c]^2 * x[c] ) @ W + b
//
// v10: hist -> scan -> scat (tile LDS bin-sort, shfl scans, lbin flush) ->
//   A: per-bin node stats (cnt/dw -> noffs, dis, y=dis*x)
//   B: FUSED per-bin node-sort (LDS) + register aggregate + 8->64 transform
//      -> out. pay2 eliminated (was 51MB round-trip); sort work overlaps
//      gather latency. r9 lesson: agg/scat were overhead-bound, not TA-bound
//      (E=3.2M lines ~ 7us floor; barrier-heavy scans ~ 20/tile).
//
// Payload pack (u64): ew_bits(32) | row(24) | lcol(8). Valid for N <= 2^24.

#define NBMAX 1024          // max bins => N <= 131072 (fallback beyond)
#define PSH   7
#define BINSZ 128
#define TILE  6144          // edges per scatter tile (LDS: 48KB payload)
#define EPT   6             // TILE / 1024 threads
#define CAP   6144          // max edges per bin staged in LDS by B

static inline size_t ws_align(size_t x) { return (x + 255) & ~(size_t)255; }

// ---- init: zero bin counters + detect int64-vs-int32 edge_index ----
__global__ void init_k(const unsigned* w, unsigned* orw, unsigned* cnt, int E) {
    int t = threadIdx.x;              // 256 threads, 1 block
    for (int i = t; i < NBMAX; i += 256) cnt[i] = 0u;
    __shared__ unsigned s;
    if (t == 0) s = 0u;
    __syncthreads();
    unsigned v = 0;
    int lim = (E < 2048) ? E : 2048;  // stay inside buffer even if int32
    for (int i = t; i < lim; i += 256)
        v |= w[2 * i + 1];            // odd words == 0 iff int64 layout
    atomicOr(&s, v);
    __syncthreads();
    if (t == 0) *orw = s;             // 0 => int64
}

// ---- histogram over destination bins ----
__global__ void hist_k(const void* ei, const unsigned* orw, unsigned* cnt,
                       int E, int NB) {
    __shared__ unsigned lh[NBMAX];
    const bool is64 = (*orw == 0u);
    const int* e32 = (const int*)ei;
    const long long* e64 = (const long long*)ei;
    for (int i = threadIdx.x; i < NB; i += blockDim.x) lh[i] = 0u;
    __syncthreads();
    int t = blockIdx.x * blockDim.x + threadIdx.x;
    int st = gridDim.x * blockDim.x;
    for (int e = t; e < E; e += st) {
        int c = is64 ? (int)e64[E + e] : e32[E + e];
        atomicAdd(&lh[c >> PSH], 1u);
    }
    __syncthreads();
    for (int i = threadIdx.x; i < NB; i += blockDim.x) {
        unsigned v = lh[i];
        if (v) atomicAdd(&cnt[i], v);
    }
}

// ---- exclusive scan of cnt[NB] -> offs[NB+1], seed cursors (shfl) ----
__global__ void scan_k(const unsigned* cnt, unsigned* offs, unsigned* gcur, int NB) {
    __shared__ unsigned wsum[16];
    int t = threadIdx.x, lane = t & 63, wv = t >> 6;   // 1024 threads
    unsigned v0 = (t < NB) ? cnt[t] : 0u;
    unsigned s = v0;
    #pragma unroll
    for (int d = 1; d < 64; d <<= 1) {
        unsigned u = __shfl_up(s, d);
        if (lane >= d) s += u;
    }
    if (lane == 63) wsum[wv] = s;
    __syncthreads();
    if (t < 16) {
        unsigned w = wsum[t];
        #pragma unroll
        for (int d = 1; d < 16; d <<= 1) {
            unsigned u = __shfl_up(w, d, 16);
            if (t >= d) w += u;
        }
        wsum[t] = w;
    }
    __syncthreads();
    unsigned excl = s - v0 + (wv ? wsum[wv - 1] : 0u);
    if (t < NB) { offs[t] = excl; gcur[t] = excl; }
    if (t == NB - 1) offs[NB] = excl + v0;
}

// ---- tile-local counting sort -> coalesced payload writes (by bin) ----
__global__ __launch_bounds__(1024)
void scat_k(const void* ei, const float* ea, const unsigned* orw,
            unsigned* gcur, unsigned long long* pay, int E, int NB, int ntiles) {
    __shared__ unsigned long long lp[TILE];   // 48KB
    __shared__ unsigned short lbin[TILE];     // 12KB: bin of sorted element
    __shared__ unsigned lh[NBMAX];
    __shared__ unsigned lo[NBMAX];
    __shared__ unsigned gb[NBMAX];
    __shared__ unsigned wsum[16];
    const bool is64 = (*orw == 0u);
    const int* e32 = (const int*)ei;
    const long long* e64 = (const long long*)ei;
    const int t = threadIdx.x, lane = t & 63, wv = t >> 6;

    for (int tile = blockIdx.x; tile < ntiles; tile += gridDim.x) {
        int base = tile * TILE;
        int tc = E - base; if (tc > TILE) tc = TILE;

        for (int i = t; i < NB; i += 1024) lh[i] = 0u;
        __syncthreads();

        int bn[EPT]; unsigned rk[EPT]; unsigned long long pv[EPT];
        #pragma unroll
        for (int i = 0; i < EPT; ++i) {
            int e = base + i * 1024 + t;
            bn[i] = -1;
            if (e < base + tc) {
                int c, r;
                if (is64) { c = (int)e64[E + e]; r = (int)e64[e]; }
                else      { c = e32[E + e];      r = e32[e]; }
                float w = ea[e];
                bn[i] = c >> PSH;
                pv[i] = ((unsigned long long)__float_as_uint(w) << 32)
                        | ((unsigned)r << 8) | (unsigned)(c & (BINSZ - 1));
                rk[i] = atomicAdd(&lh[bn[i]], 1u);
            }
        }
        __syncthreads();

        // shfl-based inclusive scan of lh -> exclusive lo (2 barriers)
        unsigned v0 = (t < NB) ? lh[t] : 0u;
        unsigned s = v0;
        #pragma unroll
        for (int d = 1; d < 64; d <<= 1) {
            unsigned u = __shfl_up(s, d);
            if (lane >= d) s += u;
        }
        if (lane == 63) wsum[wv] = s;
        __syncthreads();
        if (t < 16) {
            unsigned w = wsum[t];
            #pragma unroll
            for (int d = 1; d < 16; d <<= 1) {
                unsigned u = __shfl_up(w, d, 16);
                if (t >= d) w += u;
            }
            wsum[t] = w;
        }
        __syncthreads();
        unsigned excl = s - v0 + (wv ? wsum[wv - 1] : 0u);
        if (t < NB) {
            lo[t] = excl;
            if (v0) gb[t] = atomicAdd(&gcur[t], v0);
        }
        __syncthreads();

        // place payloads into LDS sorted by bin, recording each slot's bin
        #pragma unroll
        for (int i = 0; i < EPT; ++i)
            if (bn[i] >= 0) {
                unsigned pos = lo[bn[i]] + rk[i];
                lp[pos] = pv[i];
                lbin[pos] = (unsigned short)bn[i];
            }
        __syncthreads();

        // flush: direct bin lookup, coalesced per-bin runs
        for (int q = t; q < tc; q += 1024) {
            int a = lbin[q];
            pay[(size_t)gb[a] + (unsigned)q - lo[a]] = lp[q];
        }
        __syncthreads();
    }
}

// ---- A: per-bin node stats -> noffs, dis, y = dis*x ----
__global__ __launch_bounds__(1024)
void nodestat_k(const unsigned long long* pay, const unsigned* offs,
                unsigned* noffs, float* dis, const float* x, float* y,
                int N, int E) {
    __shared__ unsigned cnt[BINSZ];
    __shared__ float dw[BINSZ];
    __shared__ float sdis[BINSZ];
    __shared__ unsigned wpart[2];
    int b = blockIdx.x, t = threadIdx.x, lane = t & 63, wv = t >> 6;
    if (t < BINSZ) { cnt[t] = 0u; dw[t] = 0.f; }
    if (b == 0 && t == 0) noffs[N] = (unsigned)E;
    __syncthreads();
    unsigned base = offs[b], len = offs[b + 1] - base;
    for (unsigned j = t; j < len; j += 1024) {
        unsigned long long p = pay[base + j];
        unsigned lc = (unsigned)p & 255u;
        atomicAdd(&cnt[lc], 1u);
        atomicAdd(&dw[lc], __uint_as_float((unsigned)(p >> 32)));
    }
    __syncthreads();
    // scan 128 via 2 waves of shfl
    unsigned v0 = (t < BINSZ) ? cnt[t] : 0u;
    unsigned s = v0;
    #pragma unroll
    for (int d = 1; d < 64; d <<= 1) {
        unsigned u = __shfl_up(s, d);
        if (lane >= d) s += u;
    }
    if (t < BINSZ && lane == 63) wpart[wv] = s;
    __syncthreads();
    if (t < BINSZ) {
        unsigned excl = s - v0 + (wv == 1 ? wpart[0] : 0u);
        int node = b * BINSZ + t;
        float dval = 0.f;
        if (node < N) {
            noffs[node] = base + excl;
            float d = 1.0f + dw[t];
            dval = (d > 0.f) ? rsqrtf(d) : 0.f;
            dis[node] = dval;
        }
        sdis[t] = dval;
    }
    __syncthreads();
    int gi = b * (BINSZ * 8) + t;             // 1024 == BINSZ*8
    if (gi < N * 8) y[gi] = sdis[t >> 3] * x[gi];
}

// ---- B: fused per-bin node-sort (LDS) + aggregate + transform + out ----
__global__ __launch_bounds__(1024)
void aggfuse_k(const unsigned long long* pay, const unsigned* offs,
               const unsigned* noffs, const float* dis, const float* y,
               const float* Wm, const float* bv, float* out, int N) {
    __shared__ unsigned long long lp[CAP];    // 48KB sorted payload
    __shared__ float spill[BINSZ][8];         // 4KB overflow accumulator
    __shared__ unsigned loc[BINSZ];
    __shared__ unsigned cur[BINSZ];
    const float4* y4 = (const float4*)y;
    int b = blockIdx.x, t = threadIdx.x, lane = t & 63, wv = t >> 6;
    unsigned base = offs[b], len = offs[b + 1] - base;
    ((float*)spill)[t] = 0.f;                 // 1024 floats exactly
    if (t < BINSZ) {
        int node = b * BINSZ + t;
        unsigned l = (node < N) ? (noffs[node] - base) : len;
        loc[t] = l; cur[t] = l;
    }
    __syncthreads();
    // stage: rank + place sorted-by-node into LDS
    for (unsigned j = t; j < len; j += 1024) {
        unsigned long long p = pay[base + j];
        unsigned lc = (unsigned)p & 255u;
        unsigned pos = atomicAdd(&cur[lc], 1u);
        if (pos < CAP) lp[pos] = p;
        else {                                 // pathological overflow (corr.)
            unsigned r = ((unsigned)p >> 8) & 0xFFFFFFu;
            float ew = __uint_as_float((unsigned)(p >> 32));
            float4 u = y4[(size_t)r * 2], v = y4[(size_t)r * 2 + 1];
            atomicAdd(&spill[lc][0], ew * u.x); atomicAdd(&spill[lc][1], ew * u.y);
            atomicAdd(&spill[lc][2], ew * u.z); atomicAdd(&spill[lc][3], ew * u.w);
            atomicAdd(&spill[lc][4], ew * v.x); atomicAdd(&spill[lc][5], ew * v.y);
            atomicAdd(&spill[lc][6], ew * v.z); atomicAdd(&spill[lc][7], ew * v.w);
        }
    }
    __syncthreads();
    // reduce: wave wv handles local nodes wv, wv+16, ... (8 nodes)
    float wr[8];
    #pragma unroll
    for (int k = 0; k < 8; ++k) wr[k] = Wm[k * 64 + lane];
    float bj = bv[lane];
    int slot = lane >> 1, h = lane & 1;
    for (int i = 0; i < 8; ++i) {
        int ln = wv + (i << 4);
        int node = b * BINSZ + ln;
        float a0 = 0.f, a1 = 0.f, a2 = 0.f, a3 = 0.f;
        if (node < N) {
            unsigned s = loc[ln];
            unsigned e = (ln < BINSZ - 1) ? loc[ln + 1] : len;
            unsigned eL = e < CAP ? e : CAP;
            for (unsigned j = s + slot; j < eL; j += 32) {
                unsigned long long p = lp[j];
                unsigned r = ((unsigned)p >> 8) & 0xFFFFFFu;
                float ew = __uint_as_float((unsigned)(p >> 32));
                float4 v = y4[(size_t)r * 2 + h];
                a0 += ew * v.x; a1 += ew * v.y; a2 += ew * v.z; a3 += ew * v.w;
            }
        }
        #pragma unroll
        for (int m = 2; m <= 32; m <<= 1) {
            a0 += __shfl_xor(a0, m);
            a1 += __shfl_xor(a1, m);
            a2 += __shfl_xor(a2, m);
            a3 += __shfl_xor(a3, m);
        }
        float r0 = 0.f, r1 = 0.f, r2 = 0.f, r3 = 0.f;
        if (slot == 0 && node < N) {           // lanes 0 (h=0), 1 (h=1)
            float dc = dis[node];
            float4 vy = y4[(size_t)node * 2 + h];   // = dc*x[node] half-row
            r0 = dc * (a0 + spill[ln][h * 4 + 0] + vy.x);
            r1 = dc * (a1 + spill[ln][h * 4 + 1] + vy.y);
            r2 = dc * (a2 + spill[ln][h * 4 + 2] + vy.z);
            r3 = dc * (a3 + spill[ln][h * 4 + 3] + vy.w);
        }
        float g0 = __shfl(r0, 0), g1 = __shfl(r1, 0);
        float g2 = __shfl(r2, 0), g3 = __shfl(r3, 0);
        float g4 = __shfl(r0, 1), g5 = __shfl(r1, 1);
        float g6 = __shfl(r2, 1), g7 = __shfl(r3, 1);
        if (node < N) {
            float o = bj + g0 * wr[0] + g1 * wr[1] + g2 * wr[2] + g3 * wr[3]
                         + g4 * wr[4] + g5 * wr[5] + g6 * wr[6] + g7 * wr[7];
            out[(size_t)node * 64 + lane] = o;
        }
    }
}

// ---------------- round-1 fallback (tiny ws / huge N) ----------------
__global__ void fb_init_k(float* deg, float4* agg4, int N) {
    int i = blockIdx.x * blockDim.x + threadIdx.x, st = gridDim.x * blockDim.x;
    for (; i < N; i += st) {
        deg[i] = 1.0f;
        agg4[2 * i] = make_float4(0.f, 0.f, 0.f, 0.f);
        agg4[2 * i + 1] = make_float4(0.f, 0.f, 0.f, 0.f);
    }
}
__global__ void fb_deg_k(const void* ei, const float* ea, const unsigned* orw,
                         float* deg, int E) {
    const bool is64 = (*orw == 0u);
    const int* e32 = (const int*)ei;
    const long long* e64 = (const long long*)ei;
    int e = blockIdx.x * blockDim.x + threadIdx.x, st = gridDim.x * blockDim.x;
    for (; e < E; e += st) {
        int c = is64 ? (int)e64[E + e] : e32[E + e];
        atomicAdd(&deg[c], ea[e]);
    }
}
__global__ void fb_dis_k(float* deg, int N) {
    int i = blockIdx.x * blockDim.x + threadIdx.x, st = gridDim.x * blockDim.x;
    for (; i < N; i += st) {
        float d = deg[i];
        deg[i] = (d > 0.f) ? rsqrtf(d) : 0.f;
    }
}
__global__ void fb_edge_k(const void* ei, const float* ea, const unsigned* orw,
                          const float* dis, const float* x, float* agg, int E) {
    const bool is64 = (*orw == 0u);
    const int* e32 = (const int*)ei;
    const long long* e64 = (const long long*)ei;
    int e = blockIdx.x * blockDim.x + threadIdx.x, st = gridDim.x * blockDim.x;
    for (; e < E; e += st) {
        int r, c;
        if (is64) { r = (int)e64[e]; c = (int)e64[E + e]; }
        else      { r = e32[e];      c = e32[E + e]; }
        float nrm = dis[r] * ea[e] * dis[c];
        const float4* xr = (const float4*)(x + (size_t)r * 8);
        float4 a = xr[0], bb = xr[1];
        float* ag = agg + (size_t)c * 8;
        atomicAdd(ag + 0, nrm * a.x);  atomicAdd(ag + 1, nrm * a.y);
        atomicAdd(ag + 2, nrm * a.z);  atomicAdd(ag + 3, nrm * a.w);
        atomicAdd(ag + 4, nrm * bb.x); atomicAdd(ag + 5, nrm * bb.y);
        atomicAdd(ag + 6, nrm * bb.z); atomicAdd(ag + 7, nrm * bb.w);
    }
}
__global__ void fb_out_k(const float* x, const float* Wm, const float* bv,
                         const float* dis, const float* agg, float* out, int N) {
    int lane = threadIdx.x & 63;
    int wid = blockIdx.x * (blockDim.x >> 6) + (threadIdx.x >> 6);
    int nw = gridDim.x * (blockDim.x >> 6);
    float wr[8];
    #pragma unroll
    for (int k = 0; k < 8; ++k) wr[k] = Wm[k * 64 + lane];
    float bj = bv[lane];
    for (int i = wid; i < N; i += nw) {
        float d = dis[i];
        float ink = 0.f;
        if (lane < 8) ink = agg[(size_t)i * 8 + lane] + d * d * x[(size_t)i * 8 + lane];
        float acc = bj;
        #pragma unroll
        for (int k = 0; k < 8; ++k) acc += __shfl(ink, k) * wr[k];
        out[(size_t)i * 64 + lane] = acc;
    }
}

extern "C" void kernel_launch(void* const* d_in, const int* in_sizes, int n_in,
                              void* d_out, int out_size, void* d_ws, size_t ws_size,
                              hipStream_t stream) {
    const float* x  = (const float*)d_in[0];
    const void*  ei = d_in[1];
    const float* ea = (const float*)d_in[2];
    const float* Wm = (const float*)d_in[3];
    const float* bv = (const float*)d_in[4];
    float* out = (float*)d_out;

    const int N = in_sizes[0] / 8;
    const int E = in_sizes[2];
    const int NB = (N + BINSZ - 1) / BINSZ;

    char* ws = (char*)d_ws;
    size_t o = 0;
    unsigned* orw   = (unsigned*)(ws + o); o += 256;
    unsigned* cnt   = (unsigned*)(ws + o); o += ws_align(NBMAX * 4);
    unsigned* offs  = (unsigned*)(ws + o); o += ws_align((NBMAX + 1) * 4);
    unsigned* gcur  = (unsigned*)(ws + o); o += ws_align(NBMAX * 4);
    float* dis      = (float*)(ws + o);    o += ws_align((size_t)N * 4);
    unsigned* noffs = (unsigned*)(ws + o); o += ws_align((size_t)(N + 1) * 4);
    float* y        = (float*)(ws + o);    o += ws_align((size_t)N * 8 * 4);
    unsigned long long* pay = (unsigned long long*)(ws + o);
    o += ws_align((size_t)E * 8);

    const int ntiles = (E + TILE - 1) / TILE;

    if (NB <= NBMAX && E >= 2048 && o <= ws_size) {
        init_k<<<1, 256, 0, stream>>>((const unsigned*)ei, orw, cnt, E);
        hist_k<<<256, 512, 0, stream>>>(ei, orw, cnt, E, NB);
        scan_k<<<1, 1024, 0, stream>>>(cnt, offs, gcur, NB);
        scat_k<<<ntiles, 1024, 0, stream>>>(ei, ea, orw, gcur, pay, E, NB, ntiles);
        nodestat_k<<<NB, 1024, 0, stream>>>(pay, offs, noffs, dis, x, y, N, E);
        aggfuse_k<<<NB, 1024, 0, stream>>>(pay, offs, noffs, dis, y, Wm, bv, out, N);
    } else {
        float* agg = (float*)(ws + 256 + ws_align((size_t)N * 4));
        init_k<<<1, 256, 0, stream>>>((const unsigned*)ei, orw, cnt, E);
        fb_init_k<<<(N + 255) / 256, 256, 0, stream>>>(dis, (float4*)agg, N);
        fb_deg_k<<<2048, 256, 0, stream>>>(ei, ea, orw, dis, E);
        fb_dis_k<<<(N + 255) / 256, 256, 0, stream>>>(dis, N);
        fb_edge_k<<<2048, 256, 0, stream>>>(ei, ea, orw, dis, x, agg, E);
        fb_out_k<<<2048, 256, 0, stream>>>(x, Wm, bv, dis, agg, out, N);
    }
}